// Round 7
// baseline (2584.569 us; speedup 1.0000x reference)
//
#include <hip/hip_runtime.h>

#define DEV static __device__ __forceinline__

typedef __attribute__((ext_vector_type(8))) short short8;
typedef __attribute__((ext_vector_type(4))) short short4v;
typedef __attribute__((ext_vector_type(4))) float f4;

// ---- module-global workspace: bf16-converted weights (inputs are fp32)
#define OFF_QKV 0         // [4][384][128]  Q|K|V rows, k contig
#define OFF_WO  196608    // [4][128][128]
#define OFF_WG1 262144    // [4][256][128]
#define OFF_WG2 393216    // [4][128][256]
#define OFF_WC1 524288    // [4][384][128]  W0|W1|W2 concat transposed
#define OFF_WC2 720896    // [4][384][128]
#define OFF_WIN 917504    // [384][32]
#define OFF_WOUT 929792   // [16][128]
#define OFF_M1 931840     // [32][32] bf16 zero-padded (rows/cols>=21 ZERO)
#define OFF_M2 932864
#define OFF_LG 933888     // [4][32][32] zero-padded
#define W_TOT  937984

struct WSBuf {
  unsigned short w[W_TOT];
  float m1f[441];
  float m2f[441];
};
__device__ WSBuf g_ws;

DEV float b2f(unsigned short u){ union { unsigned int i; float f; } v; v.i = ((unsigned int)u)<<16; return v.f; }
// Plain bf16 RNE round (guards proven dead: all LDS finite by construction).
DEV unsigned short f2b(float f){
  union { float f; unsigned int i; } v; v.f = f;
  unsigned int i = v.i; i += 0x7fffu + ((i>>16)&1u);
  return (unsigned short)(i>>16);
}
DEV f4 mfma(short8 a, short8 b, f4 c){ return __builtin_amdgcn_mfma_f32_16x16x32_bf16(a,b,c,0,0,0); }
DEV f4 mfma16(short4v a, short4v b, f4 c){ return __builtin_amdgcn_mfma_f32_16x16x16bf16_1k(a,b,c,0,0,0); }
DEV short8 ld8(const unsigned short* p){ return *(const short8*)p; }

DEV void st4(unsigned short* p, f4 v){
  short4v o;
  o[0]=(short)f2b(v[0]); o[1]=(short)f2b(v[1]);
  o[2]=(short)f2b(v[2]); o[3]=(short)f2b(v[3]);
  *(short4v*)p = o;
}
DEV void rmw4(unsigned short* p, f4 v){
  short4v x = *(const short4v*)p;
  short4v o;
  o[0]=(short)f2b(b2f((unsigned short)x[0]) + v[0]);
  o[1]=(short)f2b(b2f((unsigned short)x[1]) + v[1]);
  o[2]=(short)f2b(b2f((unsigned short)x[2]) + v[2]);
  o[3]=(short)f2b(b2f((unsigned short)x[3]) + v[3]);
  *(short4v*)p = o;
}
DEV f4 maxz(f4 v){
  v[0]=fmaxf(v[0],0.f); v[1]=fmaxf(v[1],0.f);
  v[2]=fmaxf(v[2],0.f); v[3]=fmaxf(v[3],0.f);
  return v;
}

// ---------------- prep kernels (fp32 in -> bf16 ws) ----------------
__global__ void prep_mats(const float* __restrict__ adj,
                          const float* __restrict__ Ahat){
  __shared__ float sA[441], sL[441], sM2[441], sD[21];
  unsigned short* ws = g_ws.w;
  int t = threadIdx.x;
  if (t < 441) sA[t] = adj[t];
  __syncthreads();
  if (t < 21){ float s = 0.f; for (int j=0;j<21;++j) s += sA[t*21+j]; sD[t] = 1.0f/sqrtf(s); }
  __syncthreads();
  if (t < 441){ int i = t/21, j = t%21; sL[t] = ((i==j)?1.f:0.f) - sD[i]*sA[t]*sD[j]; }
  __syncthreads();
  if (t < 441){ int i = t/21, j = t%21; float a=0.f;
    for (int m=0;m<21;++m) a += sL[i*21+m]*sL[m*21+j];
    sM2[t] = 2.f*a - ((i==j)?1.f:0.f); }
  __syncthreads();
  for (int e = t; e < 1024; e += blockDim.x){
    int i = e>>5, j = e&31; bool v = (i<21)&&(j<21);
    ws[OFF_M1+e] = v ? f2b(sL[i*21+j]) : 0;
    ws[OFF_M2+e] = v ? f2b(sM2[i*21+j]) : 0;
  }
  if (t < 441){ g_ws.m1f[t] = sL[t]; g_ws.m2f[t] = sM2[t]; }
  for (int l=0;l<4;++l){
    __syncthreads();
    if (t < 441) sA[t] = Ahat[l*441 + t];
    __syncthreads();
    if (t < 21){ float s = 1e-5f; for (int i=0;i<21;++i) s += sA[i*21+t]; sD[t] = 1.0f/sqrtf(s); }
    __syncthreads();
    for (int e = t; e < 1024; e += blockDim.x){
      int i = e>>5, j = e&31; bool v = (i<21)&&(j<21);
      ws[OFF_LG + l*1024 + e] = v ? f2b(sD[i]*sA[i*21+j]*sD[j]) : 0;
    }
  }
}

__global__ void prep_tw(const float* __restrict__ Wq, const float* __restrict__ Wk,
                        const float* __restrict__ Wv, const float* __restrict__ Wo,
                        const float* __restrict__ Wg1, const float* __restrict__ Wg2,
                        const float* __restrict__ Wc1, const float* __restrict__ Wc2,
                        const float* __restrict__ Win, const float* __restrict__ Wout){
  unsigned short* ws = g_ws.w;
  int stride = gridDim.x*blockDim.x;
  int idx = blockIdx.x*blockDim.x + threadIdx.x;
  for (int e = idx; e < 196608; e += stride){
    int l = e/49152, r = e%49152, n = r>>7, k = r&127;
    int sel = n>>7, c = n&127;
    const float* W = (sel==0)?Wq:((sel==1)?Wk:Wv);
    ws[OFF_QKV+e] = f2b(W[l*16384 + k*128 + c]);
  }
  for (int e = idx; e < 65536; e += stride){
    int l = e>>14, r = e&16383, n = r>>7, k = r&127;
    ws[OFF_WO+e] = f2b(Wo[l*16384 + k*128 + n]);
  }
  for (int e = idx; e < 131072; e += stride){
    int l = e>>15, r = e&32767, n = r>>7, k = r&127;
    ws[OFF_WG1+e] = f2b(Wg1[l*32768 + k*256 + n]);
  }
  for (int e = idx; e < 131072; e += stride){
    int l = e>>15, r = e&32767, n = r>>8, k = r&255;
    ws[OFF_WG2+e] = f2b(Wg2[l*32768 + k*128 + n]);
  }
  for (int e = idx; e < 196608; e += stride){
    int l = e/49152, r = e%49152, n = r>>7, k = r&127;
    int sel = n>>7, c = n&127;
    ws[OFF_WC1+e] = f2b(Wc1[((l*3+sel)*128 + k)*128 + c]);
  }
  for (int e = idx; e < 196608; e += stride){
    int l = e/49152, r = e%49152, n = r>>7, k = r&127;
    int sel = n>>7, c = n&127;
    ws[OFF_WC2+e] = f2b(Wc2[((l*3+sel)*128 + k)*128 + c]);
  }
  for (int e = idx; e < 12288; e += stride){
    int n = e>>5, k = e&31, sel = n>>7, c = n&127;
    ws[OFF_WIN+e] = (k<2) ? f2b(Win[(sel*2 + k)*128 + c]) : 0;
  }
  for (int e = idx; e < 2048; e += stride){
    int n = e>>7, k = e&127;
    ws[OFF_WOUT+e] = (n<9) ? f2b(Wout[((n/3)*128 + k)*3 + (n%3)]) : 0;
  }
}

// ---------------- main kernel helpers ----------------
#define PA 152   // 16B-aligned pitches only (R16 lesson)

template<int MT, int NT, int KS>
DEV void chan_mm(const unsigned short* A, int pitchA,
                 const unsigned short* Bt, int strideB, int n0, int mt0,
                 int lane, f4 acc[MT][NT]){
  const int l16 = lane & 15, qd = lane >> 4;
#pragma unroll
  for (int ks = 0; ks < KS; ++ks){
    const int k0 = ks*32 + qd*8;
    short8 af[MT];
#pragma unroll
    for (int m=0; m<MT; ++m) af[m] = ld8(A + ((mt0+m)*16+l16)*pitchA + k0);
#pragma unroll
    for (int nt=0; nt<NT; ++nt){
      short8 bf = ld8(Bt + (n0 + nt*16 + l16)*strideB + k0);
#pragma unroll
      for (int m=0; m<MT; ++m) acc[m][nt] = mfma(af[m], bf, acc[m][nt]);
    }
  }
}

DEV void node_mm1(const unsigned short* Ut, int mt0,
                  const unsigned short* Mr, int lane, f4 acc[3][2]){
  const int l16 = lane & 15, qd = lane >> 4;
  short8 bf[2];
#pragma unroll
  for (int nt=0; nt<2; ++nt) bf[nt] = ld8(Mr + (nt*16+l16)*32 + qd*8);
#pragma unroll
  for (int b=0;b<3;++b){
    short8 af = ld8(Ut + (mt0*16 + l16)*72 + b*24 + qd*8);
#pragma unroll
    for (int nt=0;nt<2;++nt) acc[b][nt] = mfma(af, bf[nt], acc[b][nt]);
  }
}

template<int KS>
DEV void w0_term1(const unsigned short* Wt0, int sK,
                  const unsigned short* Blds, int pitchB, int mt0,
                  int lane, f4 acc[3][2]){
  const int l16 = lane&15, qd = lane>>4;
#pragma unroll
  for (int ks=0; ks<KS; ++ks){
    const int k0 = ks*32 + qd*8;
    short8 af = ld8(Wt0 + (mt0*16+l16)*sK + k0);
#pragma unroll
    for (int b=0;b<3;++b){
#pragma unroll
      for (int nt=0;nt<2;++nt){
        short8 bf = ld8(Blds + (b*21 + nt*16 + l16)*pitchB + k0);
        acc[b][nt] = mfma(af, bf, acc[b][nt]);
      }
    }
  }
}

DEV void write_tr(unsigned short* Ut, int ch, f4 v, int mt, int qd, float bias, int rmax){
#pragma unroll
  for (int reg=0; reg<4; ++reg){
    int r = mt*16 + qd*4 + reg;
    if (r < rmax){
      int b = (r>=42) ? 2 : ((r>=21)?1:0);
      int n = r - b*21;
      Ut[ch*72 + b*24 + n] = f2b(v[reg] + bias);
    }
  }
}

// ---- LDS map: TWO groups of the compact R0 74.7 KB layout in ONE block.
//   per group: R_RES [64][136]; R_A [64][PA]; R_TR K[64][136] / U[128][72]
//   (V at +8704 during attn); TRU [63][PA] (y0 / p2-stage).
#define R_RES 0
#define R_A   8704
#define R_TR  18432
#define TRU   9232
#define GSZ   37368
#define S_TOT 74736     // 149.4 KB <= 160 KB, 1 block/CU (the proven regime)

// 512-thread dual-group LN: 4 threads/row over 128 rows (2 groups x 64)
DEV void layer_norm2(unsigned short* S, const float* ga, const float* gb, int tid){
  int row = tid >> 2, seg = tid & 3;
  int g = row >> 6, r = row & 63;
  const unsigned short* p = S + g*GSZ + R_RES + r*136 + seg*32;
  float xv[32];
#pragma unroll
  for (int j=0;j<4;++j){
    short8 rv = ld8(p + j*8);
#pragma unroll
    for (int i=0;i<8;++i) xv[j*8+i] = b2f((unsigned short)rv[i]);
  }
  float s1=0.f, s2=0.f;
#pragma unroll
  for (int i=0;i<32;++i){ s1 += xv[i]; s2 += xv[i]*xv[i]; }
  s1 += __shfl_xor(s1,1); s2 += __shfl_xor(s2,1);
  s1 += __shfl_xor(s1,2); s2 += __shfl_xor(s2,2);
  float mean = s1 * 0.0078125f;
  float var = (s2 - s1*mean) * (1.0f/127.0f);
  var = fmaxf(var, 0.f);
  float inv = 1.0f/(sqrtf(var) + 1e-6f);
  unsigned short* d = S + g*GSZ + R_A + r*PA + seg*32;
#pragma unroll
  for (int j=0;j<4;++j){
    short8 ov;
#pragma unroll
    for (int i=0;i<8;++i){
      float y = ga[seg*32+j*8+i] * (xv[j*8+i]-mean) * inv + gb[seg*32+j*8+i];
      ov[i] = (short)f2b(y);
    }
    *(short8*)(d + j*8) = ov;
  }
}

// ResChebGC / input-cheb step: fused p1+p2 GEMM, NO internal barrier
// (caller loops groups, then one barrier). mode: 0 relu->st4 s_a,
// 1 relu->rmw s_res, 2 raw->st4 s_res.
template<int KS, int SK>
DEV void cheb_res(const unsigned short* Asrc, int pitchA,
                  const unsigned short* Wcat, const float* bias, int mode,
                  unsigned short* s_a, unsigned short* s_tr, unsigned short* s_res,
                  const unsigned short* M1r, const unsigned short* M2r,
                  int lane, int wave, int nb, int rvalid){
  const int l16 = lane&15, qd = lane>>4;
  const f4 z4 = {0.f,0.f,0.f,0.f};
  f4 u1[4], u2[4];
#pragma unroll
  for (int mt=0;mt<4;++mt){ u1[mt]=z4; u2[mt]=z4; }
  const unsigned short* W1p = Wcat + (128 + wave*16 + l16)*SK;
  const unsigned short* W2p = Wcat + (256 + wave*16 + l16)*SK;
#pragma unroll
  for (int ks=0;ks<KS;++ks){
    const int k0 = ks*32 + qd*8;
    short8 af[4];
#pragma unroll
    for (int m=0;m<4;++m) af[m] = ld8(Asrc + (m*16+l16)*pitchA + k0);
    short8 b1 = ld8(W1p + k0);
    short8 b2 = ld8(W2p + k0);
#pragma unroll
    for (int m=0;m<4;++m){
      u1[m] = mfma(af[m], b1, u1[m]);
      u2[m] = mfma(af[m], b2, u2[m]);
    }
  }
  int ch = wave*16 + l16;
#pragma unroll
  for (int mt=0;mt<4;++mt) write_tr(s_tr,       ch, u1[mt], mt, qd, 0.f, rvalid);
#pragma unroll
  for (int mt=0;mt<4;++mt) write_tr(s_tr + TRU, ch, u2[mt], mt, qd, 0.f, rvalid);
  // wave-local node pass (reads only own staged ch-tile rows)
  f4 a2[3][2];
#pragma unroll
  for (int b=0;b<3;++b){ a2[b][0]=z4; a2[b][1]=z4; }
  w0_term1<KS>(Wcat, SK, Asrc, pitchA, wave, lane, a2);
  node_mm1(s_tr, wave, M1r, lane, a2);
  node_mm1(s_tr + TRU, wave, M2r, lane, a2);
  const int ch0 = wave*16 + qd*4;
  const f4 vb = *(const f4*)(bias + ch0);
#pragma unroll
  for (int b=0;b<3;++b){ if (b >= nb) continue;
#pragma unroll
    for (int nt=0;nt<2;++nt){
      int o = nt*16 + l16;
      if (o < 21){
        int r = b*21 + o;
        if (mode == 0)      st4(&s_a[r*PA + ch0], maxz(a2[b][nt] + vb));
        else if (mode == 1) rmw4(&s_res[r*136 + ch0], maxz(a2[b][nt] + vb));
        else                st4(&s_res[r*136 + ch0], a2[b][nt] + vb);
      }
    }
  }
}

// ---------------- main kernel (512 threads, 8 waves, 6 samples) ----------------
// R7: dual sample-group per block. R6's barrier amortization relocated to the
// ONLY register regime that works ((512,1): 2 waves/EU -> ~256/wave budget,
// zero spill R0/R3-R5). Each phase = A-work; B-work; ONE barrier: per-sample
// barrier count halves AND each interval holds 2 independent dep chains.
__launch_bounds__(512, 1)
__global__ void graformer_main(
  const float* __restrict__ x,
  const float* __restrict__ ln1a, const float* __restrict__ ln1b,
  const float* __restrict__ ln2a, const float* __restrict__ ln2b,
  const float* __restrict__ bq, const float* __restrict__ bk,
  const float* __restrict__ bv, const float* __restrict__ bo,
  const float* __restrict__ bg1, const float* __restrict__ bg2,
  const float* __restrict__ bc1, const float* __restrict__ bc2,
  const float* __restrict__ b_in, const float* __restrict__ b_out,
  float* __restrict__ out)
{
  __shared__ __align__(16) unsigned short S[S_TOT];
  const unsigned short* ws = g_ws.w;

  const int tid = threadIdx.x;
  const int lane = tid & 63, wave = tid >> 6;   // wave in 0..7
  const int l16 = lane & 15, qd = lane >> 4;
  const int blk = blockIdx.x;
  int total = 8192 - blk*6;
  int nbA = total < 3 ? (total < 0 ? 0 : total) : 3;
  int t2 = total - 3;
  int nbB = t2 < 3 ? (t2 < 0 ? 0 : t2) : 3;
  const int rvA = nbA*21, rvB = nbB*21;
  const f4 z4 = {0.f,0.f,0.f,0.f};
  const unsigned short* M1r = ws + OFF_M1;
  const unsigned short* M2r = ws + OFF_M2;
  const int ch0 = wave*16 + qd*4;

  // finite-slack invariant: zero all LDS
  {
    short8 z8 = {0,0,0,0,0,0,0,0};
    for (int i = tid*8; i < S_TOT; i += 512*8) *(short8*)(S + i) = z8;
  }
  __syncthreads();

  // ---- stage x (fp32) into s_a_g[64][32] bf16 (both groups)
  if (tid < 128){
    int g = tid >> 6, r = tid & 63;
    int rv = g ? rvB : rvA;
    float v0=0.f, v1=0.f;
    if (r < rv){
      int b = (r>=42)?2:((r>=21)?1:0);
      int n = r - b*21;
      long gg = (long)(blk*6 + g*3 + b)*42 + n*2;
      v0 = x[gg]; v1 = x[gg+1];
    }
    unsigned short* p = S + g*GSZ + R_A + r*32;
    p[0]=f2b(v0); p[1]=f2b(v1);
#pragma unroll
    for (int k=2;k<32;++k) p[k]=0;
  }
  __syncthreads();

  // ---- input cheb per group -> s_res_g
#pragma unroll
  for (int g=0; g<2; ++g){
    unsigned short* Sg = S + g*GSZ;
    cheb_res<1,32>(Sg + R_A, 32, ws + OFF_WIN, b_in, 2,
                   Sg + R_A, Sg + R_TR, Sg + R_RES, M1r, M2r,
                   lane, wave, g?nbB:nbA, g?rvB:rvA);
  }
  __syncthreads();

  for (int l=0; l<4; ++l){
    // ---- LN1 (both groups) -> s_a_g
    layer_norm2(S, ln1a + l*128, ln1b + l*128, tid);
    __syncthreads();
    // ---- QKV: K+Q fused swapped (shared B = s_a rows); V node-quad.
    //      Q held in regs across the barrier (16/group), then packed st4.
    {
      f4 aqh[2][4];
#pragma unroll
      for (int g=0; g<2; ++g){
        unsigned short* sa = S + g*GSZ + R_A;
        unsigned short* st = S + g*GSZ + R_TR;
        const int rvg = g ? rvB : rvA;
        f4 ak[4];
#pragma unroll
        for (int nt=0;nt<4;++nt){ ak[nt]=z4; aqh[g][nt]=z4; }
        const unsigned short* WK = ws + OFF_QKV + l*49152 + 16384 + (wave*16+l16)*128;
        const unsigned short* WQ = ws + OFF_QKV + l*49152 + (wave*16+l16)*128;
#pragma unroll
        for (int ks=0;ks<4;++ks){
          const int k0 = ks*32 + qd*8;
          short8 wk = ld8(WK + k0);
          short8 wq = ld8(WQ + k0);
#pragma unroll
          for (int nt=0;nt<4;++nt){
            short8 bf = ld8(sa + (nt*16+l16)*PA + k0);
            ak[nt] = mfma(wk, bf, ak[nt]);
            aqh[g][nt] = mfma(wq, bf, aqh[g][nt]);
          }
        }
        const f4 vbk = *(const f4*)(bk + l*128 + ch0);
#pragma unroll
        for (int nt=0;nt<4;++nt){
          int node = nt*16 + l16;   // garbage rows finite, masked in softmax
          st4(&st[node*136 + ch0], ak[nt] + vbk);
        }
        // V: node-quad form (write_tr into [ch][b*24+n])
        {
          f4 av[2][2]; av[0][0]=z4; av[0][1]=z4; av[1][0]=z4; av[1][1]=z4;
          const int mh2 = (wave>>2)*2, nqv = (wave&3)*32;
          chan_mm<2,2,4>(sa, PA, ws + OFF_QKV + l*49152 + 32768, 128, nqv, mh2, lane, av);
#pragma unroll
          for (int nt=0;nt<2;++nt){
            int ch = nqv + nt*16 + l16; float bb = bv[l*128+ch];
#pragma unroll
            for (int m=0;m<2;++m) write_tr(st+8704, ch, av[m][nt], mh2+m, qd, bb, rvg);
          }
        }
      }
      __syncthreads();   // all s_a reads done; K/V visible
      const f4 vbq = *(const f4*)(bq + l*128 + ch0);
#pragma unroll
      for (int g=0; g<2; ++g){
        unsigned short* sa = S + g*GSZ + R_A;
#pragma unroll
        for (int nt=0;nt<4;++nt){
          int node = nt*16 + l16;
          st4(&sa[node*PA + ch0], aqh[g][nt] + vbq);
        }
      }
      __syncthreads();   // Q visible to all units
    }
    // ---- attention: 48 units (2 groups x 24) over 8 waves x 6.
    //      Swapped QK^T -> register softmax -> swapped PV (packed O st4).
    {
#pragma unroll
      for (int i=0;i<6;++i){
        int u = wave + 8*i;            // 0..47
        int g = (u >= 24) ? 1 : 0;
        int lu = u - 24*g;
        int pair = lu >> 1, mt = lu & 1;
        int b = pair>>2, h = pair&3;
        unsigned short* sa = S + g*GSZ + R_A;
        unsigned short* st = S + g*GSZ + R_TR;
        const int nbg = g ? nbB : nbA;
        f4 sc[2]; sc[0]=z4; sc[1]=z4;
        short8 qb = ld8(sa + (b*21 + mt*16 + l16)*PA + h*32 + qd*8);
#pragma unroll
        for (int nt=0;nt<2;++nt){
          short8 ka = ld8(st + (b*21 + nt*16 + l16)*136 + h*32 + qd*8);
          sc[nt] = mfma(ka, qb, sc[nt]);   // S^T tile: rows k, cols q
        }
        const float scale = 0.1767766952966369f; // 1/sqrt(32)
        float s0[4], s1[4];
        float m = -1e30f;
#pragma unroll
        for (int reg=0;reg<4;++reg){
          s0[reg] = sc[0][reg]*scale;                       // k = qd*4+reg (<16, valid)
          bool kv = (16 + qd*4 + reg) < 21;                 // k = 16+qd*4+reg
          s1[reg] = kv ? sc[1][reg]*scale : -1e30f;
          m = fmaxf(m, fmaxf(s0[reg], s1[reg]));
        }
        m = fmaxf(m, __shfl_xor(m,16));
        m = fmaxf(m, __shfl_xor(m,32));   // max over all k for this q=l16
        float e0[4], e1[4];
        float sum = 0.f;
#pragma unroll
        for (int reg=0;reg<4;++reg){
          e0[reg] = __expf(s0[reg]-m);
          e1[reg] = ((16+qd*4+reg)<21) ? __expf(s1[reg]-m) : 0.f;
          sum += e0[reg]+e1[reg];
        }
        sum += __shfl_xor(sum,16);
        sum += __shfl_xor(sum,32);        // sum over all k for this q=l16
        float rinv = 1.f/sum;             // sum>=1 even for garbage-q lanes (finite)
        if (b < nbg){
          short4v pa0, pa1;
#pragma unroll
          for (int reg=0;reg<4;++reg){
            pa0[reg] = (short)f2b(e0[reg]*rinv);
            pa1[reg] = (short)f2b(e1[reg]*rinv);
          }
          // PV swapped: A=V^T (row=d), B=P (col=q) -> quad along d.
          f4 oa[2]; oa[0]=z4; oa[1]=z4;
#pragma unroll
          for (int nt=0;nt<2;++nt){
            int ch = h*32 + nt*16 + l16;
            const unsigned short* vp = st + 8704 + ch*72 + b*24;
            short4v vb0 = *(const short4v*)(vp + qd*4);
            short4v vb1 = *(const short4v*)(vp + 16 + qd*4);
            oa[nt] = mfma16(vb0, pa0, oa[nt]);
            oa[nt] = mfma16(vb1, pa1, oa[nt]);
          }
          int q = mt*16 + l16;
          if (q < 21){
            int row = (b*21 + q)*PA + h*32;
#pragma unroll
            for (int nt=0;nt<2;++nt)
              st4(&sa[row + nt*16 + qd*4], oa[nt]);
          }
        }
      }
      __syncthreads();   // all O stripes visible before Wo
    }
    // ---- Wo: res += O@Wo + bo. Swapped (quad=ch -> packed rmw4), per group.
    {
#pragma unroll
      for (int g=0; g<2; ++g){
        unsigned short* sa = S + g*GSZ + R_A;
        unsigned short* sr = S + g*GSZ + R_RES;
        const int rvg = g ? rvB : rvA;
        f4 ao[1][4];
#pragma unroll
        for (int nt=0;nt<4;++nt) ao[0][nt]=z4;
        chan_mm<1,4,4>(ws + OFF_WO + l*16384, 128, sa, PA, 0, wave, lane, ao);
        const f4 vbo = *(const f4*)(bo + l*128 + ch0);
#pragma unroll
        for (int nt=0;nt<4;++nt){
          int node = nt*16 + l16;
          if (node < rvg)
            rmw4(&sr[node*136 + ch0], ao[0][nt] + vbo);
        }
      }
      __syncthreads();
    }
    // ---- LN2 (both groups) -> s_a_g
    layer_norm2(S, ln2a + l*128, ln2b + l*128, tid);
    __syncthreads();
    // ---- GraphNet: 3 barriers for both groups.
    {
      // G1: per group: WG1 fused u1+u2; stage u1 (own rows) -> node y0 ->
      //     TRU; re-stage u2 over own rows (wave-local overwrite).
#pragma unroll
      for (int g=0; g<2; ++g){
        unsigned short* sa = S + g*GSZ + R_A;
        unsigned short* st = S + g*GSZ + R_TR;
        const int nbg = g ? nbB : nbA;
        const int rvg = g ? rvB : rvA;
        f4 u1[4], u2[4];
#pragma unroll
        for (int mt=0;mt<4;++mt){ u1[mt]=z4; u2[mt]=z4; }
        const unsigned short* W1 = ws + OFF_WG1 + l*32768 + (wave*16+l16)*128;
#pragma unroll
        for (int ks=0;ks<4;++ks){
          const int k0 = ks*32 + qd*8;
          short8 af[4];
#pragma unroll
          for (int m=0;m<4;++m) af[m] = ld8(sa + (m*16+l16)*PA + k0);
          short8 b1 = ld8(W1 + k0);
          short8 b2 = ld8(W1 + 16384 + k0);
#pragma unroll
          for (int m=0;m<4;++m){
            u1[m] = mfma(af[m], b1, u1[m]);
            u2[m] = mfma(af[m], b2, u2[m]);
          }
        }
        const int ch = wave*16 + l16;
#pragma unroll
        for (int mt=0;mt<4;++mt) write_tr(st, ch, u1[mt], mt, qd, 0.f, rvg);
        f4 y[3][2];
#pragma unroll
        for (int b=0;b<3;++b){ y[b][0]=z4; y[b][1]=z4; }
        node_mm1(st, wave, ws + OFF_LG + l*1024, lane, y);
        const f4 vb1 = *(const f4*)(bg1 + l*256 + ch0);
#pragma unroll
        for (int b=0;b<3;++b){ if (b>=nbg) continue;
#pragma unroll
          for (int nt=0;nt<2;++nt){
            int o = nt*16+l16;
            if (o<21){ int r = b*21+o;
              st4(&st[TRU + r*PA + ch0], maxz(y[b][nt] + vb1));
            }
          }
        }
#pragma unroll
        for (int mt=0;mt<4;++mt) write_tr(st, ch, u2[mt], mt, qd, 0.f, rvg);
      }
      __syncthreads();   // B1: s_a (LN2) reads done; u2 staged; y0 in TRU
      // G2: per group: node u2 (own rows) -> y1 -> s_a
#pragma unroll
      for (int g=0; g<2; ++g){
        unsigned short* sa = S + g*GSZ + R_A;
        unsigned short* st = S + g*GSZ + R_TR;
        const int nbg = g ? nbB : nbA;
        f4 y[3][2];
#pragma unroll
        for (int b=0;b<3;++b){ y[b][0]=z4; y[b][1]=z4; }
        node_mm1(st, wave, ws + OFF_LG + l*1024, lane, y);
        const f4 vb1b = *(const f4*)(bg1 + l*256 + 128 + ch0);
#pragma unroll
        for (int b=0;b<3;++b){ if (b>=nbg) continue;
#pragma unroll
          for (int nt=0;nt<2;++nt){
            int o = nt*16+l16;
            if (o<21){ int r = b*21+o;
              st4(&sa[r*PA + ch0], maxz(y[b][nt] + vb1b));
            }
          }
        }
      }
      __syncthreads();   // B2: y1 (s_a) + y0 (TRU) visible
      // G3: per group: WG2 fused (y0 from TRU, y1 from s_a) -> Z; stage Z
      //     wave-local; node -> fz; rmw s_res.
#pragma unroll
      for (int g=0; g<2; ++g){
        unsigned short* sa = S + g*GSZ + R_A;
        unsigned short* st = S + g*GSZ + R_TR;
        unsigned short* sr = S + g*GSZ + R_RES;
        const int nbg = g ? nbB : nbA;
        const int rvg = g ? rvB : rvA;
        f4 Z[4];
#pragma unroll
        for (int mt=0;mt<4;++mt) Z[mt]=z4;
        const unsigned short* W2 = ws + OFF_WG2 + l*32768 + (wave*16+l16)*256;
#pragma unroll
        for (int ks=0;ks<4;++ks){
          const int k0 = ks*32 + qd*8;
          short8 a0[4], a1[4];
#pragma unroll
          for (int m=0;m<4;++m) a0[m] = ld8(st + TRU + (m*16+l16)*PA + k0);
#pragma unroll
          for (int m=0;m<4;++m) a1[m] = ld8(sa + (m*16+l16)*PA + k0);
          short8 b0 = ld8(W2 + k0);
          short8 b1 = ld8(W2 + 128 + k0);
#pragma unroll
          for (int m=0;m<4;++m){
            Z[m] = mfma(a0[m], b0, Z[m]);
            Z[m] = mfma(a1[m], b1, Z[m]);
          }
        }
        const int ch = wave*16 + l16;
#pragma unroll
        for (int mt=0;mt<4;++mt) write_tr(st, ch, Z[mt], mt, qd, 0.f, rvg);
        f4 fz[3][2];
#pragma unroll
        for (int b=0;b<3;++b){ fz[b][0]=z4; fz[b][1]=z4; }
        node_mm1(st, wave, ws + OFF_LG + l*1024, lane, fz);
        const f4 vb2 = *(const f4*)(bg2 + l*128 + ch0);
#pragma unroll
        for (int b=0;b<3;++b){ if (b>=nbg) continue;
#pragma unroll
          for (int nt=0;nt<2;++nt){
            int o = nt*16+l16;
            if (o<21){ int r = b*21+o;
              rmw4(&sr[r*136 + ch0], fz[b][nt] + vb2);
            }
          }
        }
      }
      __syncthreads();   // B4: s_res complete
    }
    // ---- ResChebGC: g = relu(cheb1(res)) -> s_a; res += relu(cheb2(g))
#pragma unroll
    for (int g=0; g<2; ++g){
      unsigned short* Sg = S + g*GSZ;
      cheb_res<4,128>(Sg + R_RES, 136, ws + OFF_WC1 + l*49152, bc1 + l*128, 0,
                      Sg + R_A, Sg + R_TR, Sg + R_RES, M1r, M2r,
                      lane, wave, g?nbB:nbA, g?rvB:rvA);
    }
    __syncthreads();
#pragma unroll
    for (int g=0; g<2; ++g){
      unsigned short* Sg = S + g*GSZ;
      cheb_res<4,128>(Sg + R_A, PA, ws + OFF_WC2 + l*49152, bc2 + l*128, 1,
                      Sg + R_A, Sg + R_TR, Sg + R_RES, M1r, M2r,
                      lane, wave, g?nbB:nbA, g?rvB:rvA);
    }
    __syncthreads();
  }

  // ---- final cheb -> out (fp32): waves 0-3 group A rows, waves 4-7 group B
  {
    f4 acc = z4;
    const int g = wave >> 2, wv = wave & 3;
    const unsigned short* sr = S + g*GSZ + R_RES;
#pragma unroll
    for (int ks=0;ks<4;++ks){
      int k0 = ks*32 + qd*8;
      short8 af = ld8(sr + (wv*16 + l16)*136 + k0);
      short8 bf = ld8(ws + OFF_WOUT + l16*128 + k0);
      acc = mfma(af, bf, acc);
    }
    float* sf = (float*)(S + g*GSZ + R_A);
    if (l16 < 9){
#pragma unroll
      for (int reg=0;reg<4;++reg){
        int r = wv*16 + qd*4 + reg;
        if (r < 63) sf[r*12 + l16] = acc[reg];
      }
    }
    __syncthreads();
    if (tid < 378){
      int g2 = (tid >= 189) ? 1 : 0;
      int t = tid - 189*g2;
      int r = t/3, c = t - r*3;
      int b = (r>=42)?2:((r>=21)?1:0);
      int n = r - b*21;
      const int nbg = g2 ? nbB : nbA;
      if (b < nbg){
        const float* M1f = g_ws.m1f;
        const float* M2f = g_ws.m2f;
        const float* sf2 = (const float*)(S + g2*GSZ + R_A);
        float a = sf2[r*12 + c] + b_out[c];
        for (int m=0;m<21;++m){
          a += M1f[n*21+m]*sf2[(b*21+m)*12 + 3 + c];
          a += M2f[n*21+m]*sf2[(b*21+m)*12 + 6 + c];
        }
        out[((long)(blk*6 + g2*3 + b)*21 + n)*3 + c] = a;
      }
    }
  }
}

extern "C" void kernel_launch(void* const* d_in, const int* in_sizes, int n_in,
                              void* d_out, int out_size, void* d_ws, size_t ws_size,
                              hipStream_t stream){
  const float* x    = (const float*)d_in[0];
  // d_in[1] = mask (all ones) -- unused
  const float* adj  = (const float*)d_in[2];
  const float* Win  = (const float*)d_in[3];
  const float* b_in = (const float*)d_in[4];
  const float* Wout = (const float*)d_in[5];
  const float* b_out= (const float*)d_in[6];
  const float* ln1a = (const float*)d_in[7];
  const float* ln1b = (const float*)d_in[8];
  const float* ln2a = (const float*)d_in[9];
  const float* ln2b = (const float*)d_in[10];
  const float* Wq = (const float*)d_in[11];
  const float* bq = (const float*)d_in[12];
  const float* Wk = (const float*)d_in[13];
  const float* bk = (const float*)d_in[14];
  const float* Wv = (const float*)d_in[15];
  const float* bv = (const float*)d_in[16];
  const float* Wo = (const float*)d_in[17];
  const float* bo = (const float*)d_in[18];
  const float* Ahat = (const float*)d_in[19];
  const float* Wg1 = (const float*)d_in[20];
  const float* bg1 = (const float*)d_in[21];
  const float* Wg2 = (const float*)d_in[22];
  const float* bg2 = (const float*)d_in[23];
  const float* Wc1 = (const float*)d_in[24];
  const float* bc1 = (const float*)d_in[25];
  const float* Wc2 = (const float*)d_in[26];
  const float* bc2 = (const float*)d_in[27];
  float* outp = (float*)d_out;

  hipLaunchKernelGGL(prep_mats, dim3(1), dim3(512), 0, stream, adj, Ahat);
  hipLaunchKernelGGL(prep_tw, dim3(512), dim3(256), 0, stream,
                     Wq, Wk, Wv, Wo, Wg1, Wg2, Wc1, Wc2, Win, Wout);
  hipLaunchKernelGGL(graformer_main, dim3(1366), dim3(512), 0, stream,
                     x, ln1a, ln1b, ln2a, ln2b, bq, bk, bv, bo,
                     bg1, bg2, bc1, bc2, b_in, b_out, outp);
}

// Round 8
// 1285.924 us; speedup vs baseline: 2.0099x; 2.0099x over previous
//
#include <hip/hip_runtime.h>

#define DEV static __device__ __forceinline__

typedef __attribute__((ext_vector_type(8))) short short8;
typedef __attribute__((ext_vector_type(4))) short short4v;
typedef __attribute__((ext_vector_type(4))) float f4;
typedef __attribute__((ext_vector_type(2))) unsigned int uint2v;
typedef __attribute__((ext_vector_type(4))) unsigned int uint4v;

// ---- module-global workspace: bf16-converted weights (inputs are fp32)
#define OFF_QKV 0         // [4][384][128]  Q|K|V rows, k contig
#define OFF_WO  196608    // [4][128][128]
#define OFF_WG1 262144    // [4][256][128]
#define OFF_WG2 393216    // [4][128][256]
#define OFF_WC1 524288    // [4][384][128]  W0|W1|W2 concat transposed
#define OFF_WC2 720896    // [4][384][128]
#define OFF_WIN 917504    // [384][32]
#define OFF_WOUT 929792   // [16][128]
#define OFF_M1 931840     // [32][32] bf16 zero-padded (rows/cols>=21 ZERO)
#define OFF_M2 932864
#define OFF_LG 933888     // [4][32][32] zero-padded
#define W_TOT  937984

struct WSBuf {
  unsigned short w[W_TOT];
  float m1f[441];
  float m2f[441];
};
__device__ WSBuf g_ws;

DEV float b2f(unsigned short u){ union { unsigned int i; float f; } v; v.i = ((unsigned int)u)<<16; return v.f; }
// Plain bf16 RNE round — used only in prep kernels (not perf-critical).
DEV unsigned short f2b(float f){
  union { float f; unsigned int i; } v; v.f = f;
  unsigned int i = v.i; i += 0x7fffu + ((i>>16)&1u);
  return (unsigned short)(i>>16);
}
// R8: single-op packed bf16 convert (RNE, bit-identical to f2b) for the
// main kernel's epilogues. v_cvt_pk_bf16_f32 has no builtin on gfx950 —
// inline asm per T12/m240. dst[15:0]=cvt(src0), dst[31:16]=cvt(src1).
DEV unsigned int pk2(float lo, float hi){
  unsigned int r;
  asm("v_cvt_pk_bf16_f32 %0, %1, %2" : "=v"(r) : "v"(lo), "v"(hi));
  return r;
}
DEV unsigned short f2b1(float f){ return (unsigned short)pk2(f, f); }

DEV f4 mfma(short8 a, short8 b, f4 c){ return __builtin_amdgcn_mfma_f32_16x16x32_bf16(a,b,c,0,0,0); }
DEV f4 mfma16(short4v a, short4v b, f4 c){ return __builtin_amdgcn_mfma_f32_16x16x16bf16_1k(a,b,c,0,0,0); }
DEV short8 ld8(const unsigned short* p){ return *(const short8*)p; }

DEV void st4(unsigned short* p, f4 v){
  uint2v o; o[0] = pk2(v[0], v[1]); o[1] = pk2(v[2], v[3]);
  *(uint2v*)p = o;
}
DEV void rmw4(unsigned short* p, f4 v){
  short4v x = *(const short4v*)p;
  uint2v o;
  o[0] = pk2(b2f((unsigned short)x[0]) + v[0], b2f((unsigned short)x[1]) + v[1]);
  o[1] = pk2(b2f((unsigned short)x[2]) + v[2], b2f((unsigned short)x[3]) + v[3]);
  *(uint2v*)p = o;
}
DEV f4 maxz(f4 v){
  v[0]=fmaxf(v[0],0.f); v[1]=fmaxf(v[1],0.f);
  v[2]=fmaxf(v[2],0.f); v[3]=fmaxf(v[3],0.f);
  return v;
}

// ---------------- prep kernels (fp32 in -> bf16 ws) ----------------
__global__ void prep_mats(const float* __restrict__ adj,
                          const float* __restrict__ Ahat){
  __shared__ float sA[441], sL[441], sM2[441], sD[21];
  unsigned short* ws = g_ws.w;
  int t = threadIdx.x;
  if (t < 441) sA[t] = adj[t];
  __syncthreads();
  if (t < 21){ float s = 0.f; for (int j=0;j<21;++j) s += sA[t*21+j]; sD[t] = 1.0f/sqrtf(s); }
  __syncthreads();
  if (t < 441){ int i = t/21, j = t%21; sL[t] = ((i==j)?1.f:0.f) - sD[i]*sA[t]*sD[j]; }
  __syncthreads();
  if (t < 441){ int i = t/21, j = t%21; float a=0.f;
    for (int m=0;m<21;++m) a += sL[i*21+m]*sL[m*21+j];
    sM2[t] = 2.f*a - ((i==j)?1.f:0.f); }
  __syncthreads();
  for (int e = t; e < 1024; e += blockDim.x){
    int i = e>>5, j = e&31; bool v = (i<21)&&(j<21);
    ws[OFF_M1+e] = v ? f2b(sL[i*21+j]) : 0;
    ws[OFF_M2+e] = v ? f2b(sM2[i*21+j]) : 0;
  }
  if (t < 441){ g_ws.m1f[t] = sL[t]; g_ws.m2f[t] = sM2[t]; }
  for (int l=0;l<4;++l){
    __syncthreads();
    if (t < 441) sA[t] = Ahat[l*441 + t];
    __syncthreads();
    if (t < 21){ float s = 1e-5f; for (int i=0;i<21;++i) s += sA[i*21+t]; sD[t] = 1.0f/sqrtf(s); }
    __syncthreads();
    for (int e = t; e < 1024; e += blockDim.x){
      int i = e>>5, j = e&31; bool v = (i<21)&&(j<21);
      ws[OFF_LG + l*1024 + e] = v ? f2b(sD[i]*sA[i*21+j]*sD[j]) : 0;
    }
  }
}

__global__ void prep_tw(const float* __restrict__ Wq, const float* __restrict__ Wk,
                        const float* __restrict__ Wv, const float* __restrict__ Wo,
                        const float* __restrict__ Wg1, const float* __restrict__ Wg2,
                        const float* __restrict__ Wc1, const float* __restrict__ Wc2,
                        const float* __restrict__ Win, const float* __restrict__ Wout){
  unsigned short* ws = g_ws.w;
  int stride = gridDim.x*blockDim.x;
  int idx = blockIdx.x*blockDim.x + threadIdx.x;
  for (int e = idx; e < 196608; e += stride){
    int l = e/49152, r = e%49152, n = r>>7, k = r&127;
    int sel = n>>7, c = n&127;
    const float* W = (sel==0)?Wq:((sel==1)?Wk:Wv);
    ws[OFF_QKV+e] = f2b(W[l*16384 + k*128 + c]);
  }
  for (int e = idx; e < 65536; e += stride){
    int l = e>>14, r = e&16383, n = r>>7, k = r&127;
    ws[OFF_WO+e] = f2b(Wo[l*16384 + k*128 + n]);
  }
  for (int e = idx; e < 131072; e += stride){
    int l = e>>15, r = e&32767, n = r>>7, k = r&127;
    ws[OFF_WG1+e] = f2b(Wg1[l*32768 + k*256 + n]);
  }
  for (int e = idx; e < 131072; e += stride){
    int l = e>>15, r = e&32767, n = r>>8, k = r&255;
    ws[OFF_WG2+e] = f2b(Wg2[l*32768 + k*128 + n]);
  }
  for (int e = idx; e < 196608; e += stride){
    int l = e/49152, r = e%49152, n = r>>7, k = r&127;
    int sel = n>>7, c = n&127;
    ws[OFF_WC1+e] = f2b(Wc1[((l*3+sel)*128 + k)*128 + c]);
  }
  for (int e = idx; e < 196608; e += stride){
    int l = e/49152, r = e%49152, n = r>>7, k = r&127;
    int sel = n>>7, c = n&127;
    ws[OFF_WC2+e] = f2b(Wc2[((l*3+sel)*128 + k)*128 + c]);
  }
  for (int e = idx; e < 12288; e += stride){
    int n = e>>5, k = e&31, sel = n>>7, c = n&127;
    ws[OFF_WIN+e] = (k<2) ? f2b(Win[(sel*2 + k)*128 + c]) : 0;
  }
  for (int e = idx; e < 2048; e += stride){
    int n = e>>7, k = e&127;
    ws[OFF_WOUT+e] = (n<9) ? f2b(Wout[((n/3)*128 + k)*3 + (n%3)]) : 0;
  }
}

// ---------------- main kernel helpers ----------------
#define PA 152   // 16B-aligned pitches only (R16 lesson)

template<int MT, int NT, int KS>
DEV void chan_mm(const unsigned short* A, int pitchA,
                 const unsigned short* Bt, int strideB, int n0, int mt0,
                 int lane, f4 acc[MT][NT]){
  const int l16 = lane & 15, qd = lane >> 4;
#pragma unroll
  for (int ks = 0; ks < KS; ++ks){
    const int k0 = ks*32 + qd*8;
    short8 af[MT];
#pragma unroll
    for (int m=0; m<MT; ++m) af[m] = ld8(A + ((mt0+m)*16+l16)*pitchA + k0);
#pragma unroll
    for (int nt=0; nt<NT; ++nt){
      short8 bf = ld8(Bt + (n0 + nt*16 + l16)*strideB + k0);
#pragma unroll
      for (int m=0; m<MT; ++m) acc[m][nt] = mfma(af[m], bf, acc[m][nt]);
    }
  }
}

DEV void node_mm1(const unsigned short* Ut, int mt0,
                  const unsigned short* Mr, int lane, f4 acc[3][2]){
  const int l16 = lane & 15, qd = lane >> 4;
  short8 bf[2];
#pragma unroll
  for (int nt=0; nt<2; ++nt) bf[nt] = ld8(Mr + (nt*16+l16)*32 + qd*8);
#pragma unroll
  for (int b=0;b<3;++b){
    short8 af = ld8(Ut + (mt0*16 + l16)*72 + b*24 + qd*8);
#pragma unroll
    for (int nt=0;nt<2;++nt) acc[b][nt] = mfma(af, bf[nt], acc[b][nt]);
  }
}

template<int KS>
DEV void w0_term1(const unsigned short* Wt0, int sK,
                  const unsigned short* Blds, int pitchB, int mt0,
                  int lane, f4 acc[3][2]){
  const int l16 = lane&15, qd = lane>>4;
#pragma unroll
  for (int ks=0; ks<KS; ++ks){
    const int k0 = ks*32 + qd*8;
    short8 af = ld8(Wt0 + (mt0*16+l16)*sK + k0);
#pragma unroll
    for (int b=0;b<3;++b){
#pragma unroll
      for (int nt=0;nt<2;++nt){
        short8 bf = ld8(Blds + (b*21 + nt*16 + l16)*pitchB + k0);
        acc[b][nt] = mfma(af, bf, acc[b][nt]);
      }
    }
  }
}

DEV void write_tr(unsigned short* Ut, int ch, f4 v, int mt, int qd, float bias, int rmax){
#pragma unroll
  for (int reg=0; reg<4; ++reg){
    int r = mt*16 + qd*4 + reg;
    if (r < rmax){
      int b = (r>=42) ? 2 : ((r>=21)?1:0);
      int n = r - b*21;
      Ut[ch*72 + b*24 + n] = f2b1(v[reg] + bias);
    }
  }
}

// 512-thread LN: 8 threads/row, 16 ch each; cvt_pk epilogue (R8)
DEV void layer_norm(const unsigned short* src, unsigned short* dst,
                    const float* ga, const float* gb, int tid){
  int row = tid >> 3, seg = tid & 7;
  const unsigned short* p = src + row*136 + seg*16;
  float xv[16];
#pragma unroll
  for (int j=0;j<2;++j){
    short8 rv = ld8(p + j*8);
#pragma unroll
    for (int i=0;i<8;++i) xv[j*8+i] = b2f((unsigned short)rv[i]);
  }
  float s1=0.f, s2=0.f;
#pragma unroll
  for (int i=0;i<16;++i){ s1 += xv[i]; s2 += xv[i]*xv[i]; }
  s1 += __shfl_xor(s1,1); s2 += __shfl_xor(s2,1);
  s1 += __shfl_xor(s1,2); s2 += __shfl_xor(s2,2);
  s1 += __shfl_xor(s1,4); s2 += __shfl_xor(s2,4);
  float mean = s1 * 0.0078125f;
  float var = (s2 - s1*mean) * (1.0f/127.0f);
  var = fmaxf(var, 0.f);
  float inv = 1.0f/(sqrtf(var) + 1e-6f);
  unsigned short* d = dst + row*PA + seg*16;
#pragma unroll
  for (int j=0;j<2;++j){
    uint4v ov;
#pragma unroll
    for (int k=0;k<4;++k){
      float y0 = ga[seg*16+j*8+2*k  ] * (xv[j*8+2*k  ]-mean) * inv + gb[seg*16+j*8+2*k  ];
      float y1 = ga[seg*16+j*8+2*k+1] * (xv[j*8+2*k+1]-mean) * inv + gb[seg*16+j*8+2*k+1];
      ov[k] = pk2(y0, y1);
    }
    *(uint4v*)(d + j*8) = ov;
  }
}

// ---- LDS map (ushort elems). 1 block/CU, 2 waves/EU, 128-arch-VGPR cap is
// the ONLY viable regime (R1/R2/R6/R7 all spill-closed). Dedicated regions
// buy barrier removal (R4); GEMM-pair fusion buys ILP (R5).
#define R_RES 0
#define R_A   8704
#define R_TR  18432
#define TRU   9232      // p2/y0 base = S+27664
#define R_Q   37368
#define R_Y1  47096
#define S_TOT 56824     // 113.6 KB

// ResChebGC step: fused p1+p2 GEMM (shared A), zero internal barriers.
DEV void cheb_res(const unsigned short* Asrc, int pitchA,
                  const unsigned short* Wcat, const float* bias,
                  bool writeG,
                  unsigned short* s_a, unsigned short* s_tr, unsigned short* s_res,
                  const unsigned short* M1r, const unsigned short* M2r,
                  int lane, int wave, int nb, int rvalid){
  const int l16 = lane&15, qd = lane>>4;
  const f4 z4 = {0.f,0.f,0.f,0.f};
  f4 u1[4], u2[4];
#pragma unroll
  for (int mt=0;mt<4;++mt){ u1[mt]=z4; u2[mt]=z4; }
#pragma unroll
  for (int ks=0;ks<4;++ks){
    const int k0 = ks*32 + qd*8;
    short8 af[4];
#pragma unroll
    for (int m=0;m<4;++m) af[m] = ld8(Asrc + (m*16+l16)*pitchA + k0);
    short8 b1 = ld8(Wcat + (128 + wave*16 + l16)*128 + k0);
    short8 b2 = ld8(Wcat + (256 + wave*16 + l16)*128 + k0);
#pragma unroll
    for (int m=0;m<4;++m){
      u1[m] = mfma(af[m], b1, u1[m]);
      u2[m] = mfma(af[m], b2, u2[m]);
    }
  }
  int ch = wave*16 + l16;
#pragma unroll
  for (int mt=0;mt<4;++mt) write_tr(s_tr,       ch, u1[mt], mt, qd, 0.f, rvalid);
#pragma unroll
  for (int mt=0;mt<4;++mt) write_tr(s_tr + TRU, ch, u2[mt], mt, qd, 0.f, rvalid);
  // wave-local: node reads only its own staged ch-tile; w0 GEMM covers the
  // LDS round-trip.
  f4 a2[3][2];
#pragma unroll
  for (int b=0;b<3;++b){ a2[b][0]=z4; a2[b][1]=z4; }
  w0_term1<4>(Wcat, 128, Asrc, pitchA, wave, lane, a2);
  node_mm1(s_tr, wave, M1r, lane, a2);
  node_mm1(s_tr + TRU, wave, M2r, lane, a2);
  const int ch0 = wave*16 + qd*4;
  const f4 vb = *(const f4*)(bias + ch0);
#pragma unroll
  for (int b=0;b<3;++b){ if (b >= nb) continue;
#pragma unroll
    for (int nt=0;nt<2;++nt){
      int o = nt*16 + l16;
      if (o < 21){
        int r = b*21 + o;
        f4 t = maxz(a2[b][nt] + vb);
        if (writeG) st4(&s_a[r*PA + ch0], t);
        else        rmw4(&s_res[r*136 + ch0], t);
      }
    }
  }
  __syncthreads();
}

// ---------------- main kernel (512 threads, 8 waves) ----------------
// R5 structure (best measured: 1352 us) + R8 cvt_pk epilogues.
__launch_bounds__(512, 1)
__global__ void graformer_main(
  const float* __restrict__ x,
  const float* __restrict__ ln1a, const float* __restrict__ ln1b,
  const float* __restrict__ ln2a, const float* __restrict__ ln2b,
  const float* __restrict__ bq, const float* __restrict__ bk,
  const float* __restrict__ bv, const float* __restrict__ bo,
  const float* __restrict__ bg1, const float* __restrict__ bg2,
  const float* __restrict__ bc1, const float* __restrict__ bc2,
  const float* __restrict__ b_in, const float* __restrict__ b_out,
  float* __restrict__ out)
{
  __shared__ __align__(16) unsigned short S[S_TOT];
  unsigned short* s_res = S + R_RES;
  unsigned short* s_a   = S + R_A;
  unsigned short* s_tr  = S + R_TR;
  unsigned short* s_q   = S + R_Q;
  unsigned short* s_y1  = S + R_Y1;
  const unsigned short* ws = g_ws.w;

  const int tid = threadIdx.x;
  const int lane = tid & 63, wave = tid >> 6;   // wave in 0..7
  const int l16 = lane & 15, qd = lane >> 4;
  const int blk = blockIdx.x;
  int nb = 8192 - blk*3; nb = (nb < 3) ? nb : 3;
  const int rvalid = nb*21;
  const f4 z4 = {0.f,0.f,0.f,0.f};
  const unsigned short* M1r = ws + OFF_M1;
  const unsigned short* M2r = ws + OFF_M2;
  const int ch0 = wave*16 + qd*4;

  // finite-slack invariant: zero all LDS
  {
    short8 z8 = {0,0,0,0,0,0,0,0};
    for (int i = tid*8; i < S_TOT; i += 512*8) *(short8*)(S + i) = z8;
  }
  __syncthreads();

  // ---- stage x (fp32) into s_a[64][32] bf16
  if (tid < 64){
    int r = tid;
    float v0=0.f, v1=0.f;
    if (r < rvalid){
      int b = (r>=42)?2:((r>=21)?1:0);
      int n = r - b*21;
      long g = (long)(blk*3+b)*42 + n*2;
      v0 = x[g]; v1 = x[g+1];
    }
    unsigned short* p = s_a + r*32;
    p[0]=f2b1(v0); p[1]=f2b1(v1);
#pragma unroll
    for (int k=2;k<32;++k) p[k]=0;
  }
  __syncthreads();

  // ---- input cheb: res = x@W0 + M1@(x@W1) + M2@(x@W2) + b_in
  {
#pragma unroll
    for (int p=1; p<=2; ++p){
      f4 acc[4][1];
#pragma unroll
      for (int mt=0;mt<4;++mt) acc[mt][0]=z4;
      chan_mm<4,1,1>(s_a, 32, ws + OFF_WIN, 32, p*128 + wave*16, 0, lane, acc);
      unsigned short* Ut = (p==1) ? s_tr : (s_tr + TRU);
      int ch = wave*16 + l16;
#pragma unroll
      for (int mt=0;mt<4;++mt) write_tr(Ut, ch, acc[mt][0], mt, qd, 0.f, rvalid);
    }
    f4 a2[3][2];
#pragma unroll
    for (int b=0;b<3;++b){ a2[b][0]=z4; a2[b][1]=z4; }
    w0_term1<1>(ws + OFF_WIN, 32, s_a, 32, wave, lane, a2);
    node_mm1(s_tr, wave, M1r, lane, a2);
    node_mm1(s_tr + TRU, wave, M2r, lane, a2);
    const f4 vbin = *(const f4*)(b_in + ch0);
#pragma unroll
    for (int b=0;b<3;++b){ if (b>=nb) continue;
#pragma unroll
      for (int nt=0;nt<2;++nt){
        int o = nt*16 + l16;
        if (o < 21){ int r = b*21 + o;
          st4(&s_res[r*136 + ch0], a2[b][nt] + vbin);
        }
      }
    }
    __syncthreads();
  }

  for (int l=0; l<4; ++l){
    // ---- LN1 -> s_a
    layer_norm(s_res, s_a, ln1a + l*128, ln1b + l*128, tid);
    __syncthreads();
    // ---- QKV: ONE barrier. K+Q fused (swapped, shared B = s_a rows);
    //      Q -> dedicated s_q (packed st4). V node-quad.
    {
      {
        f4 ak[4], aq[4];
#pragma unroll
        for (int nt=0;nt<4;++nt){ ak[nt]=z4; aq[nt]=z4; }
        const unsigned short* WK = ws + OFF_QKV + l*49152 + 16384;
        const unsigned short* WQ = ws + OFF_QKV + l*49152;
#pragma unroll
        for (int ks=0;ks<4;++ks){
          const int k0 = ks*32 + qd*8;
          short8 wk = ld8(WK + (wave*16+l16)*128 + k0);
          short8 wq = ld8(WQ + (wave*16+l16)*128 + k0);
#pragma unroll
          for (int nt=0;nt<4;++nt){
            short8 bf = ld8(s_a + (nt*16+l16)*PA + k0);
            ak[nt] = mfma(wk, bf, ak[nt]);
            aq[nt] = mfma(wq, bf, aq[nt]);
          }
        }
        const f4 vbk = *(const f4*)(bk + l*128 + ch0);
        const f4 vbq = *(const f4*)(bq + l*128 + ch0);
#pragma unroll
        for (int nt=0;nt<4;++nt){
          int node = nt*16 + l16;   // garbage rows finite, masked in softmax
          st4(&s_tr[node*136 + ch0], ak[nt] + vbk);
          st4(&s_q[node*PA + ch0], aq[nt] + vbq);
        }
      }
      // V: node-quad form (write_tr into [ch][b*24+n]) — layout needed by PV
      {
        f4 av[2][2]; av[0][0]=z4; av[0][1]=z4; av[1][0]=z4; av[1][1]=z4;
        const int mh2 = (wave>>2)*2, nq = (wave&3)*32;
        chan_mm<2,2,4>(s_a, PA, ws + OFF_QKV + l*49152 + 32768, 128, nq, mh2, lane, av);
#pragma unroll
        for (int nt=0;nt<2;++nt){
          int ch = nq + nt*16 + l16; float bb = bv[l*128+ch];
#pragma unroll
          for (int m=0;m<2;++m) write_tr(s_tr+8704, ch, av[m][nt], mh2+m, qd, bb, rvalid);
        }
      }
      __syncthreads();   // K/V/Q visible; s_a free for O
    }
    // ---- attention: 24 (pair, mt) units over 8 waves x 3 — balanced.
    //      Swapped QK^T -> register softmax -> swapped PV (packed O st4).
    {
#pragma unroll
      for (int i=0;i<3;++i){
        int u = wave + 8*i;            // 0..23
        int pair = u >> 1, mt = u & 1;
        int b = pair>>2, h = pair&3;
        f4 sc[2]; sc[0]=z4; sc[1]=z4;
        short8 qb = ld8(s_q + (b*21 + mt*16 + l16)*PA + h*32 + qd*8);
#pragma unroll
        for (int nt=0;nt<2;++nt){
          short8 ka = ld8(s_tr + (b*21 + nt*16 + l16)*136 + h*32 + qd*8);
          sc[nt] = mfma(ka, qb, sc[nt]);   // S^T tile: rows k, cols q
        }
        const float scale = 0.1767766952966369f; // 1/sqrt(32)
        float s0[4], s1[4];
        float m = -1e30f;
#pragma unroll
        for (int reg=0;reg<4;++reg){
          s0[reg] = sc[0][reg]*scale;                       // k = qd*4+reg (<16, valid)
          bool kv = (16 + qd*4 + reg) < 21;                 // k = 16+qd*4+reg
          s1[reg] = kv ? sc[1][reg]*scale : -1e30f;
          m = fmaxf(m, fmaxf(s0[reg], s1[reg]));
        }
        m = fmaxf(m, __shfl_xor(m,16));
        m = fmaxf(m, __shfl_xor(m,32));   // max over all k for this q=l16
        float e0[4], e1[4];
        float sum = 0.f;
#pragma unroll
        for (int reg=0;reg<4;++reg){
          e0[reg] = __expf(s0[reg]-m);
          e1[reg] = ((16+qd*4+reg)<21) ? __expf(s1[reg]-m) : 0.f;
          sum += e0[reg]+e1[reg];
        }
        sum += __shfl_xor(sum,16);
        sum += __shfl_xor(sum,32);        // sum over all k for this q=l16
        float rinv = 1.f/sum;             // sum>=1 even for garbage-q lanes (finite)
        if (b < nb){
          uint2v t0, t1;
          t0[0] = pk2(e0[0]*rinv, e0[1]*rinv);
          t0[1] = pk2(e0[2]*rinv, e0[3]*rinv);
          t1[0] = pk2(e1[0]*rinv, e1[1]*rinv);
          t1[1] = pk2(e1[2]*rinv, e1[3]*rinv);
          short4v pa0 = *(short4v*)&t0;
          short4v pa1 = *(short4v*)&t1;
          // PV swapped: A=V^T (row=d), B=P (col=q) -> quad along d.
          f4 oa[2]; oa[0]=z4; oa[1]=z4;
#pragma unroll
          for (int nt=0;nt<2;++nt){
            int ch = h*32 + nt*16 + l16;
            const unsigned short* vp = s_tr + 8704 + ch*72 + b*24;
            short4v vb0 = *(const short4v*)(vp + qd*4);
            short4v vb1 = *(const short4v*)(vp + 16 + qd*4);
            oa[nt] = mfma16(vb0, pa0, oa[nt]);
            oa[nt] = mfma16(vb1, pa1, oa[nt]);
          }
          int q = mt*16 + l16;
          if (q < 21){
            int row = (b*21 + q)*PA + h*32;
#pragma unroll
            for (int nt=0;nt<2;++nt)
              st4(&s_a[row + nt*16 + qd*4], oa[nt]);
          }
        }
      }
      __syncthreads();   // all O stripes visible before Wo
    }
    // ---- Wo: res += O@Wo + bo. Swapped (quad=ch -> packed rmw4).
    {
      f4 ao[1][4];
#pragma unroll
      for (int nt=0;nt<4;++nt) ao[0][nt]=z4;
      chan_mm<1,4,4>(ws + OFF_WO + l*16384, 128, s_a, PA, 0, wave, lane, ao);
      const f4 vbo = *(const f4*)(bo + l*128 + ch0);
#pragma unroll
      for (int nt=0;nt<4;++nt){
        int node = nt*16 + l16;
        if (node < rvalid)
          rmw4(&s_res[node*136 + ch0], ao[0][nt] + vbo);
      }
      __syncthreads();
    }
    // ---- LN2 -> s_a
    layer_norm(s_res, s_a, ln2a + l*128, ln2b + l*128, tid);
    __syncthreads();
    // ---- GraphNet: 2 barriers. WG1 h0+h1 fused (shared A = s_a rows);
    //      WG2 y0/y1 streams interleaved.
    {
      f4 u1[4], u2[4];
#pragma unroll
      for (int mt=0;mt<4;++mt){ u1[mt]=z4; u2[mt]=z4; }
      {
        const unsigned short* W1 = ws + OFF_WG1 + l*32768;
#pragma unroll
        for (int ks=0;ks<4;++ks){
          const int k0 = ks*32 + qd*8;
          short8 af[4];
#pragma unroll
          for (int m=0;m<4;++m) af[m] = ld8(s_a + (m*16+l16)*PA + k0);
          short8 b1 = ld8(W1 + (wave*16+l16)*128 + k0);
          short8 b2 = ld8(W1 + 16384 + (wave*16+l16)*128 + k0);
#pragma unroll
          for (int m=0;m<4;++m){
            u1[m] = mfma(af[m], b1, u1[m]);
            u2[m] = mfma(af[m], b2, u2[m]);
          }
        }
      }
      int ch = wave*16 + l16;
      // half0: stage u1 (own ch rows) -> node -> y0 -> TRU
      {
#pragma unroll
        for (int mt=0;mt<4;++mt) write_tr(s_tr, ch, u1[mt], mt, qd, 0.f, rvalid);
        f4 y[3][2];
#pragma unroll
        for (int b=0;b<3;++b){ y[b][0]=z4; y[b][1]=z4; }
        node_mm1(s_tr, wave, ws + OFF_LG + l*1024, lane, y);
        const f4 vb1 = *(const f4*)(bg1 + l*256 + ch0);
#pragma unroll
        for (int b=0;b<3;++b){ if (b>=nb) continue;
#pragma unroll
          for (int nt=0;nt<2;++nt){
            int o = nt*16+l16;
            if (o<21){ int r = b*21+o;
              st4(&s_tr[TRU + r*PA + ch0], maxz(y[b][nt] + vb1));
            }
          }
        }
      }
      // half1: re-stage own s_tr rows with u2 (wave-local overwrite)
      {
#pragma unroll
        for (int mt=0;mt<4;++mt) write_tr(s_tr, ch, u2[mt], mt, qd, 0.f, rvalid);
        f4 y[3][2];
#pragma unroll
        for (int b=0;b<3;++b){ y[b][0]=z4; y[b][1]=z4; }
        node_mm1(s_tr, wave, ws + OFF_LG + l*1024, lane, y);
        const f4 vb1b = *(const f4*)(bg1 + l*256 + 128 + ch0);
#pragma unroll
        for (int b=0;b<3;++b){ if (b>=nb) continue;
#pragma unroll
          for (int nt=0;nt<2;++nt){
            int o = nt*16+l16;
            if (o<21){ int r = b*21+o;
              st4(&s_y1[r*PA + ch0], maxz(y[b][nt] + vb1b));
            }
          }
        }
      }
      __syncthreads();   // B2: y0(TRU) + y1(s_y1) visible
      // WG2: y0/y1 streams interleaved
      f4 Z[4];
#pragma unroll
      for (int mt=0;mt<4;++mt) Z[mt]=z4;
      {
        const unsigned short* W2 = ws + OFF_WG2 + l*32768;
#pragma unroll
        for (int ks=0;ks<4;++ks){
          const int k0 = ks*32 + qd*8;
          short8 a0[4], a1[4];
#pragma unroll
          for (int m=0;m<4;++m) a0[m] = ld8(s_tr + TRU + (m*16+l16)*PA + k0);
#pragma unroll
          for (int m=0;m<4;++m) a1[m] = ld8(s_y1 + (m*16+l16)*PA + k0);
          short8 b0 = ld8(W2 + (wave*16+l16)*256 + k0);
          short8 b1 = ld8(W2 + (wave*16+l16)*256 + 128 + k0);
#pragma unroll
          for (int m=0;m<4;++m){
            Z[m] = mfma(a0[m], b0, Z[m]);
            Z[m] = mfma(a1[m], b1, Z[m]);
          }
        }
      }
      // Z^T staging into s_tr (own ch rows, wave-local) -> NO barrier
      {
#pragma unroll
        for (int mt=0;mt<4;++mt) write_tr(s_tr, ch, Z[mt], mt, qd, 0.f, rvalid);
      }
      f4 fz[3][2];
#pragma unroll
      for (int b=0;b<3;++b){ fz[b][0]=z4; fz[b][1]=z4; }
      node_mm1(s_tr, wave, ws + OFF_LG + l*1024, lane, fz);   // wave-local
      {
        const f4 vb2 = *(const f4*)(bg2 + l*128 + ch0);
#pragma unroll
        for (int b=0;b<3;++b){ if (b>=nb) continue;
#pragma unroll
          for (int nt=0;nt<2;++nt){
            int o = nt*16+l16;
            if (o<21){ int r = b*21+o;
              rmw4(&s_res[r*136 + ch0], fz[b][nt] + vb2);
            }
          }
        }
      }
      __syncthreads();   // B4: s_res complete
    }
    // ---- ResChebGC: g = relu(cheb1(res)) -> s_a; res += relu(cheb2(g))
    cheb_res(s_res, 136, ws + OFF_WC1 + l*49152, bc1 + l*128, true,
             s_a, s_tr, s_res, M1r, M2r, lane, wave, nb, rvalid);
    cheb_res(s_a, PA, ws + OFF_WC2 + l*49152, bc2 + l*128, false,
             s_a, s_tr, s_res, M1r, M2r, lane, wave, nb, rvalid);
  }

  // ---- final cheb -> out (fp32), node part in fp32 VALU
  {
    f4 acc = z4;
    if (wave < 4){
#pragma unroll
      for (int ks=0;ks<4;++ks){
        int k0 = ks*32 + qd*8;
        short8 af = ld8(s_res + (wave*16 + l16)*136 + k0);
        short8 bf = ld8(ws + OFF_WOUT + l16*128 + k0);
        acc = mfma(af, bf, acc);
      }
    }
    float* sf = (float*)s_a;
    if (wave < 4 && l16 < 9){
#pragma unroll
      for (int reg=0;reg<4;++reg){
        int r = wave*16 + qd*4 + reg;
        if (r < 63) sf[r*12 + l16] = acc[reg];
      }
    }
    __syncthreads();
    if (tid < 189){
      int r = tid/3, c = tid - r*3;
      int b = (r>=42)?2:((r>=21)?1:0);
      int n = r - b*21;
      if (b < nb){
        const float* M1f = g_ws.m1f;
        const float* M2f = g_ws.m2f;
        float a = sf[r*12 + c] + b_out[c];
        for (int m=0;m<21;++m){
          a += M1f[n*21+m]*sf[(b*21+m)*12 + 3 + c];
          a += M2f[n*21+m]*sf[(b*21+m)*12 + 6 + c];
        }
        out[((long)(blk*3+b)*21 + n)*3 + c] = a;
      }
    }
  }
}

extern "C" void kernel_launch(void* const* d_in, const int* in_sizes, int n_in,
                              void* d_out, int out_size, void* d_ws, size_t ws_size,
                              hipStream_t stream){
  const float* x    = (const float*)d_in[0];
  // d_in[1] = mask (all ones) -- unused
  const float* adj  = (const float*)d_in[2];
  const float* Win  = (const float*)d_in[3];
  const float* b_in = (const float*)d_in[4];
  const float* Wout = (const float*)d_in[5];
  const float* b_out= (const float*)d_in[6];
  const float* ln1a = (const float*)d_in[7];
  const float* ln1b = (const float*)d_in[8];
  const float* ln2a = (const float*)d_in[9];
  const float* ln2b = (const float*)d_in[10];
  const float* Wq = (const float*)d_in[11];
  const float* bq = (const float*)d_in[12];
  const float* Wk = (const float*)d_in[13];
  const float* bk = (const float*)d_in[14];
  const float* Wv = (const float*)d_in[15];
  const float* bv = (const float*)d_in[16];
  const float* Wo = (const float*)d_in[17];
  const float* bo = (const float*)d_in[18];
  const float* Ahat = (const float*)d_in[19];
  const float* Wg1 = (const float*)d_in[20];
  const float* bg1 = (const float*)d_in[21];
  const float* Wg2 = (const float*)d_in[22];
  const float* bg2 = (const float*)d_in[23];
  const float* Wc1 = (const float*)d_in[24];
  const float* bc1 = (const float*)d_in[25];
  const float* Wc2 = (const float*)d_in[26];
  const float* bc2 = (const float*)d_in[27];
  float* outp = (float*)d_out;

  hipLaunchKernelGGL(prep_mats, dim3(1), dim3(512), 0, stream, adj, Ahat);
  hipLaunchKernelGGL(prep_tw, dim3(512), dim3(256), 0, stream,
                     Wq, Wk, Wv, Wo, Wg1, Wg2, Wc1, Wc2, Win, Wout);
  hipLaunchKernelGGL(graformer_main, dim3(2731), dim3(512), 0, stream,
                     x, ln1a, ln1b, ln2a, ln2b, bq, bk, bv, bo,
                     bg1, bg2, bc1, bc2, b_in, b_out, outp);
}

// Round 9
// 1179.475 us; speedup vs baseline: 2.1913x; 1.0903x over previous
//
#include <hip/hip_runtime.h>

#define DEV static __device__ __forceinline__

typedef __attribute__((ext_vector_type(8))) short short8;
typedef __attribute__((ext_vector_type(4))) short short4v;
typedef __attribute__((ext_vector_type(4))) float f4;
typedef __attribute__((ext_vector_type(2))) unsigned int uint2v;
typedef __attribute__((ext_vector_type(4))) unsigned int uint4v;

// ---- module-global workspace: bf16-converted weights (inputs are fp32)
#define OFF_QKV 0         // [4][384][128]  Q|K|V rows, k contig
#define OFF_WO  196608    // [4][128][128]
#define OFF_WG1 262144    // [4][256][128]
#define OFF_WG2 393216    // [4][128][256]
#define OFF_WC1 524288    // [4][384][128]  W0|W1|W2 concat transposed
#define OFF_WC2 720896    // [4][384][128]
#define OFF_WIN 917504    // [384][32]
#define OFF_WOUT 929792   // [16][128]
#define OFF_M1 931840     // [32][32] bf16 zero-padded (rows/cols>=21 ZERO)
#define OFF_M2 932864
#define OFF_LG 933888     // [4][32][32] zero-padded
#define W_TOT  937984

struct WSBuf {
  unsigned short w[W_TOT];
  float m1f[441];
  float m2f[441];
};
__device__ WSBuf g_ws;

DEV float b2f(unsigned short u){ union { unsigned int i; float f; } v; v.i = ((unsigned int)u)<<16; return v.f; }
// Plain bf16 RNE round — used only in prep kernels (not perf-critical).
DEV unsigned short f2b(float f){
  union { float f; unsigned int i; } v; v.f = f;
  unsigned int i = v.i; i += 0x7fffu + ((i>>16)&1u);
  return (unsigned short)(i>>16);
}
// R8: single-op packed bf16 convert (RNE, bit-identical to f2b).
DEV unsigned int pk2(float lo, float hi){
  unsigned int r;
  asm("v_cvt_pk_bf16_f32 %0, %1, %2" : "=v"(r) : "v"(lo), "v"(hi));
  return r;
}
DEV unsigned short f2b1(float f){ return (unsigned short)pk2(f, f); }

DEV f4 mfma(short8 a, short8 b, f4 c){ return __builtin_amdgcn_mfma_f32_16x16x32_bf16(a,b,c,0,0,0); }
DEV f4 mfma16(short4v a, short4v b, f4 c){ return __builtin_amdgcn_mfma_f32_16x16x16bf16_1k(a,b,c,0,0,0); }
DEV short8 ld8(const unsigned short* p){ return *(const short8*)p; }

DEV void st4(unsigned short* p, f4 v){
  uint2v o; o[0] = pk2(v[0], v[1]); o[1] = pk2(v[2], v[3]);
  *(uint2v*)p = o;
}
DEV void rmw4(unsigned short* p, f4 v){
  short4v x = *(const short4v*)p;
  uint2v o;
  o[0] = pk2(b2f((unsigned short)x[0]) + v[0], b2f((unsigned short)x[1]) + v[1]);
  o[1] = pk2(b2f((unsigned short)x[2]) + v[2], b2f((unsigned short)x[3]) + v[3]);
  *(uint2v*)p = o;
}
DEV f4 maxz(f4 v){
  v[0]=fmaxf(v[0],0.f); v[1]=fmaxf(v[1],0.f);
  v[2]=fmaxf(v[2],0.f); v[3]=fmaxf(v[3],0.f);
  return v;
}

// ---------------- prep kernels (fp32 in -> bf16 ws) ----------------
__global__ void prep_mats(const float* __restrict__ adj,
                          const float* __restrict__ Ahat){
  __shared__ float sA[441], sL[441], sM2[441], sD[21];
  unsigned short* ws = g_ws.w;
  int t = threadIdx.x;
  if (t < 441) sA[t] = adj[t];
  __syncthreads();
  if (t < 21){ float s = 0.f; for (int j=0;j<21;++j) s += sA[t*21+j]; sD[t] = 1.0f/sqrtf(s); }
  __syncthreads();
  if (t < 441){ int i = t/21, j = t%21; sL[t] = ((i==j)?1.f:0.f) - sD[i]*sA[t]*sD[j]; }
  __syncthreads();
  if (t < 441){ int i = t/21, j = t%21; float a=0.f;
    for (int m=0;m<21;++m) a += sL[i*21+m]*sL[m*21+j];
    sM2[t] = 2.f*a - ((i==j)?1.f:0.f); }
  __syncthreads();
  for (int e = t; e < 1024; e += blockDim.x){
    int i = e>>5, j = e&31; bool v = (i<21)&&(j<21);
    ws[OFF_M1+e] = v ? f2b(sL[i*21+j]) : 0;
    ws[OFF_M2+e] = v ? f2b(sM2[i*21+j]) : 0;
  }
  if (t < 441){ g_ws.m1f[t] = sL[t]; g_ws.m2f[t] = sM2[t]; }
  for (int l=0;l<4;++l){
    __syncthreads();
    if (t < 441) sA[t] = Ahat[l*441 + t];
    __syncthreads();
    if (t < 21){ float s = 1e-5f; for (int i=0;i<21;++i) s += sA[i*21+t]; sD[t] = 1.0f/sqrtf(s); }
    __syncthreads();
    for (int e = t; e < 1024; e += blockDim.x){
      int i = e>>5, j = e&31; bool v = (i<21)&&(j<21);
      ws[OFF_LG + l*1024 + e] = v ? f2b(sD[i]*sA[i*21+j]*sD[j]) : 0;
    }
  }
}

__global__ void prep_tw(const float* __restrict__ Wq, const float* __restrict__ Wk,
                        const float* __restrict__ Wv, const float* __restrict__ Wo,
                        const float* __restrict__ Wg1, const float* __restrict__ Wg2,
                        const float* __restrict__ Wc1, const float* __restrict__ Wc2,
                        const float* __restrict__ Win, const float* __restrict__ Wout){
  unsigned short* ws = g_ws.w;
  int stride = gridDim.x*blockDim.x;
  int idx = blockIdx.x*blockDim.x + threadIdx.x;
  for (int e = idx; e < 196608; e += stride){
    int l = e/49152, r = e%49152, n = r>>7, k = r&127;
    int sel = n>>7, c = n&127;
    const float* W = (sel==0)?Wq:((sel==1)?Wk:Wv);
    ws[OFF_QKV+e] = f2b(W[l*16384 + k*128 + c]);
  }
  for (int e = idx; e < 65536; e += stride){
    int l = e>>14, r = e&16383, n = r>>7, k = r&127;
    ws[OFF_WO+e] = f2b(Wo[l*16384 + k*128 + n]);
  }
  for (int e = idx; e < 131072; e += stride){
    int l = e>>15, r = e&32767, n = r>>7, k = r&127;
    ws[OFF_WG1+e] = f2b(Wg1[l*32768 + k*256 + n]);
  }
  for (int e = idx; e < 131072; e += stride){
    int l = e>>15, r = e&32767, n = r>>8, k = r&255;
    ws[OFF_WG2+e] = f2b(Wg2[l*32768 + k*128 + n]);
  }
  for (int e = idx; e < 196608; e += stride){
    int l = e/49152, r = e%49152, n = r>>7, k = r&127;
    int sel = n>>7, c = n&127;
    ws[OFF_WC1+e] = f2b(Wc1[((l*3+sel)*128 + k)*128 + c]);
  }
  for (int e = idx; e < 196608; e += stride){
    int l = e/49152, r = e%49152, n = r>>7, k = r&127;
    int sel = n>>7, c = n&127;
    ws[OFF_WC2+e] = f2b(Wc2[((l*3+sel)*128 + k)*128 + c]);
  }
  for (int e = idx; e < 12288; e += stride){
    int n = e>>5, k = e&31, sel = n>>7, c = n&127;
    ws[OFF_WIN+e] = (k<2) ? f2b(Win[(sel*2 + k)*128 + c]) : 0;
  }
  for (int e = idx; e < 2048; e += stride){
    int n = e>>7, k = e&127;
    ws[OFF_WOUT+e] = (n<9) ? f2b(Wout[((n/3)*128 + k)*3 + (n%3)]) : 0;
  }
}

// ---------------- main kernel helpers ----------------
#define PA 152   // 16B-aligned pitches only (R16 lesson)

template<int MT, int NT, int KS>
DEV void chan_mm(const unsigned short* A, int pitchA,
                 const unsigned short* Bt, int strideB, int n0, int mt0,
                 int lane, f4 acc[MT][NT]){
  const int l16 = lane & 15, qd = lane >> 4;
#pragma unroll
  for (int ks = 0; ks < KS; ++ks){
    const int k0 = ks*32 + qd*8;
    short8 af[MT];
#pragma unroll
    for (int m=0; m<MT; ++m) af[m] = ld8(A + ((mt0+m)*16+l16)*pitchA + k0);
#pragma unroll
    for (int nt=0; nt<NT; ++nt){
      short8 bf = ld8(Bt + (n0 + nt*16 + l16)*strideB + k0);
#pragma unroll
      for (int m=0; m<MT; ++m) acc[m][nt] = mfma(af[m], bf, acc[m][nt]);
    }
  }
}

DEV void node_mm1(const unsigned short* Ut, int mt0,
                  const unsigned short* Mr, int lane, f4 acc[3][2]){
  const int l16 = lane & 15, qd = lane >> 4;
  short8 bf[2];
#pragma unroll
  for (int nt=0; nt<2; ++nt) bf[nt] = ld8(Mr + (nt*16+l16)*32 + qd*8);
#pragma unroll
  for (int b=0;b<3;++b){
    short8 af = ld8(Ut + (mt0*16 + l16)*72 + b*24 + qd*8);
#pragma unroll
    for (int nt=0;nt<2;++nt) acc[b][nt] = mfma(af, bf[nt], acc[b][nt]);
  }
}

template<int KS>
DEV void w0_term1(const unsigned short* Wt0, int sK,
                  const unsigned short* Blds, int pitchB, int mt0,
                  int lane, f4 acc[3][2]){
  const int l16 = lane&15, qd = lane>>4;
#pragma unroll
  for (int ks=0; ks<KS; ++ks){
    const int k0 = ks*32 + qd*8;
    short8 af = ld8(Wt0 + (mt0*16+l16)*sK + k0);
#pragma unroll
    for (int b=0;b<3;++b){
#pragma unroll
      for (int nt=0;nt<2;++nt){
        short8 bf = ld8(Blds + (b*21 + nt*16 + l16)*pitchB + k0);
        acc[b][nt] = mfma(af, bf, acc[b][nt]);
      }
    }
  }
}

// R9: staging store with PRECOMPUTED addressing. chBase = (wave*16+l16)*72
// (thread-const); wpk packs the 4 byte-offsets (b*24+n) for this mt;
// wmask bit (mt*4+reg) = row-valid. ~3 VALU/store vs write_tr's ~7.
DEV void write_tr2(unsigned short* Ut, int chBase, f4 v,
                   unsigned wpk, unsigned wmask, int mt){
#pragma unroll
  for (int reg=0; reg<4; ++reg){
    if (wmask & (1u << (mt*4+reg)))
      Ut[chBase + ((wpk >> (8*reg)) & 0xffu)] = f2b1(v[reg]);
  }
}

// 512-thread LN: 8 threads/row, 16 ch each; cvt_pk epilogue (R8)
DEV void layer_norm(const unsigned short* src, unsigned short* dst,
                    const float* ga, const float* gb, int tid){
  int row = tid >> 3, seg = tid & 7;
  const unsigned short* p = src + row*136 + seg*16;
  float xv[16];
#pragma unroll
  for (int j=0;j<2;++j){
    short8 rv = ld8(p + j*8);
#pragma unroll
    for (int i=0;i<8;++i) xv[j*8+i] = b2f((unsigned short)rv[i]);
  }
  float s1=0.f, s2=0.f;
#pragma unroll
  for (int i=0;i<16;++i){ s1 += xv[i]; s2 += xv[i]*xv[i]; }
  s1 += __shfl_xor(s1,1); s2 += __shfl_xor(s2,1);
  s1 += __shfl_xor(s1,2); s2 += __shfl_xor(s2,2);
  s1 += __shfl_xor(s1,4); s2 += __shfl_xor(s2,4);
  float mean = s1 * 0.0078125f;
  float var = (s2 - s1*mean) * (1.0f/127.0f);
  var = fmaxf(var, 0.f);
  float inv = 1.0f/(sqrtf(var) + 1e-6f);
  unsigned short* d = dst + row*PA + seg*16;
#pragma unroll
  for (int j=0;j<2;++j){
    uint4v ov;
#pragma unroll
    for (int k=0;k<4;++k){
      float y0 = ga[seg*16+j*8+2*k  ] * (xv[j*8+2*k  ]-mean) * inv + gb[seg*16+j*8+2*k  ];
      float y1 = ga[seg*16+j*8+2*k+1] * (xv[j*8+2*k+1]-mean) * inv + gb[seg*16+j*8+2*k+1];
      ov[k] = pk2(y0, y1);
    }
    *(uint4v*)(d + j*8) = ov;
  }
}

// ---- LDS map (ushort elems). 1 block/CU, 2 waves/EU, 128-arch-VGPR cap is
// the ONLY viable regime (R1/R2/R6/R7 all spill-closed).
#define R_RES 0
#define R_A   8704
#define R_TR  18432
#define TRU   9232      // p2/y0 base = S+27664
#define R_Q   37368
#define R_Y1  47096
#define S_TOT 56824     // 113.6 KB

// ResChebGC step: fused p1+p2 GEMM (shared A), zero internal barriers.
DEV void cheb_res(const unsigned short* Asrc, int pitchA,
                  const unsigned short* Wcat, const float* bias,
                  bool writeG,
                  unsigned short* s_a, unsigned short* s_tr, unsigned short* s_res,
                  const unsigned short* M1r, const unsigned short* M2r,
                  int lane, int wave, int nb, int rvalid,
                  int chBase, const unsigned* wpack, unsigned wmask){
  const int l16 = lane&15, qd = lane>>4;
  const f4 z4 = {0.f,0.f,0.f,0.f};
  f4 u1[4], u2[4];
#pragma unroll
  for (int mt=0;mt<4;++mt){ u1[mt]=z4; u2[mt]=z4; }
#pragma unroll
  for (int ks=0;ks<4;++ks){
    const int k0 = ks*32 + qd*8;
    short8 af[4];
#pragma unroll
    for (int m=0;m<4;++m) af[m] = ld8(Asrc + (m*16+l16)*pitchA + k0);
    short8 b1 = ld8(Wcat + (128 + wave*16 + l16)*128 + k0);
    short8 b2 = ld8(Wcat + (256 + wave*16 + l16)*128 + k0);
#pragma unroll
    for (int m=0;m<4;++m){
      u1[m] = mfma(af[m], b1, u1[m]);
      u2[m] = mfma(af[m], b2, u2[m]);
    }
  }
#pragma unroll
  for (int mt=0;mt<4;++mt) write_tr2(s_tr,       chBase, u1[mt], wpack[mt], wmask, mt);
#pragma unroll
  for (int mt=0;mt<4;++mt) write_tr2(s_tr + TRU, chBase, u2[mt], wpack[mt], wmask, mt);
  // wave-local: node reads only its own staged ch-tile; w0 GEMM covers the
  // LDS round-trip.
  f4 a2[3][2];
#pragma unroll
  for (int b=0;b<3;++b){ a2[b][0]=z4; a2[b][1]=z4; }
  w0_term1<4>(Wcat, 128, Asrc, pitchA, wave, lane, a2);
  node_mm1(s_tr, wave, M1r, lane, a2);
  node_mm1(s_tr + TRU, wave, M2r, lane, a2);
  const int ch0 = wave*16 + qd*4;
  const f4 vb = *(const f4*)(bias + ch0);
#pragma unroll
  for (int b=0;b<3;++b){ if (b >= nb) continue;
#pragma unroll
    for (int nt=0;nt<2;++nt){
      int o = nt*16 + l16;
      if (o < 21){
        int r = b*21 + o;
        f4 t = maxz(a2[b][nt] + vb);
        if (writeG) st4(&s_a[r*PA + ch0], t);
        else        rmw4(&s_res[r*136 + ch0], t);
      }
    }
  }
  __syncthreads();
}

// ---------------- main kernel (512 threads, 8 waves) ----------------
// R5/R8 structure + R9: QKV 3-chain fusion + precomputed staging addresses.
__launch_bounds__(512, 1)
__global__ void graformer_main(
  const float* __restrict__ x,
  const float* __restrict__ ln1a, const float* __restrict__ ln1b,
  const float* __restrict__ ln2a, const float* __restrict__ ln2b,
  const float* __restrict__ bq, const float* __restrict__ bk,
  const float* __restrict__ bv, const float* __restrict__ bo,
  const float* __restrict__ bg1, const float* __restrict__ bg2,
  const float* __restrict__ bc1, const float* __restrict__ bc2,
  const float* __restrict__ b_in, const float* __restrict__ b_out,
  float* __restrict__ out)
{
  __shared__ __align__(16) unsigned short S[S_TOT];
  unsigned short* s_res = S + R_RES;
  unsigned short* s_a   = S + R_A;
  unsigned short* s_tr  = S + R_TR;
  unsigned short* s_q   = S + R_Q;
  unsigned short* s_y1  = S + R_Y1;
  const unsigned short* ws = g_ws.w;

  const int tid = threadIdx.x;
  const int lane = tid & 63, wave = tid >> 6;   // wave in 0..7
  const int l16 = lane & 15, qd = lane >> 4;
  const int blk = blockIdx.x;
  int nb = 8192 - blk*3; nb = (nb < 3) ? nb : 3;
  const int rvalid = nb*21;
  const f4 z4 = {0.f,0.f,0.f,0.f};
  const unsigned short* M1r = ws + OFF_M1;
  const unsigned short* M2r = ws + OFF_M2;
  const int ch0 = wave*16 + qd*4;

  // R9 precompute: staging-store addressing (thread-const).
  // write_tr2: Ut[chBase + (b*24+n)] where r = mt*16+qd*4+reg.
  unsigned wpack[4]; unsigned wmask = 0;
#pragma unroll
  for (int mt=0;mt<4;++mt){
    unsigned pk = 0;
#pragma unroll
    for (int reg=0;reg<4;++reg){
      int r = mt*16 + qd*4 + reg;
      int b = (r>=42)?2:((r>=21)?1:0);
      pk |= (unsigned)(b*24 + (r - b*21)) << (8*reg);
      if (r < rvalid) wmask |= 1u << (mt*4+reg);
    }
    wpack[mt] = pk;
  }
  const int chBase = (wave*16 + l16)*72;
  // V column offsets: node = nt*16+l16 -> b*24+n, valid bit per nt.
  int vcolo[4]; unsigned vmask = 0;
#pragma unroll
  for (int nt=0;nt<4;++nt){
    int node = nt*16 + l16;
    int b = (node>=42)?2:((node>=21)?1:0);
    vcolo[nt] = b*24 + (node - b*21);
    if (node < rvalid) vmask |= 1u << nt;
  }

  // finite-slack invariant: zero all LDS
  {
    short8 z8 = {0,0,0,0,0,0,0,0};
    for (int i = tid*8; i < S_TOT; i += 512*8) *(short8*)(S + i) = z8;
  }
  __syncthreads();

  // ---- stage x (fp32) into s_a[64][32] bf16
  if (tid < 64){
    int r = tid;
    float v0=0.f, v1=0.f;
    if (r < rvalid){
      int b = (r>=42)?2:((r>=21)?1:0);
      int n = r - b*21;
      long g = (long)(blk*3+b)*42 + n*2;
      v0 = x[g]; v1 = x[g+1];
    }
    unsigned short* p = s_a + r*32;
    p[0]=f2b1(v0); p[1]=f2b1(v1);
#pragma unroll
    for (int k=2;k<32;++k) p[k]=0;
  }
  __syncthreads();

  // ---- input cheb: res = x@W0 + M1@(x@W1) + M2@(x@W2) + b_in
  {
#pragma unroll
    for (int p=1; p<=2; ++p){
      f4 acc[4][1];
#pragma unroll
      for (int mt=0;mt<4;++mt) acc[mt][0]=z4;
      chan_mm<4,1,1>(s_a, 32, ws + OFF_WIN, 32, p*128 + wave*16, 0, lane, acc);
      unsigned short* Ut = (p==1) ? s_tr : (s_tr + TRU);
#pragma unroll
      for (int mt=0;mt<4;++mt) write_tr2(Ut, chBase, acc[mt][0], wpack[mt], wmask, mt);
    }
    f4 a2[3][2];
#pragma unroll
    for (int b=0;b<3;++b){ a2[b][0]=z4; a2[b][1]=z4; }
    w0_term1<1>(ws + OFF_WIN, 32, s_a, 32, wave, lane, a2);
    node_mm1(s_tr, wave, M1r, lane, a2);
    node_mm1(s_tr + TRU, wave, M2r, lane, a2);
    const f4 vbin = *(const f4*)(b_in + ch0);
#pragma unroll
    for (int b=0;b<3;++b){ if (b>=nb) continue;
#pragma unroll
      for (int nt=0;nt<2;++nt){
        int o = nt*16 + l16;
        if (o < 21){ int r = b*21 + o;
          st4(&s_res[r*136 + ch0], a2[b][nt] + vbin);
        }
      }
    }
    __syncthreads();
  }

  for (int l=0; l<4; ++l){
    // ---- LN1 -> s_a
    layer_norm(s_res, s_a, ln1a + l*128, ln1b + l*128, tid);
    __syncthreads();
    // ---- QKV: ONE barrier, ONE fused 3-chain loop (K,Q,V share the s_a
    //      B-reads — halves the phase's LDS read traffic). K,Q: packed st4
    //      ([node][ch] layouts). V: V^T[ch][colo(node)] scatter with
    //      precomputed column offsets (bias folded).
    {
      f4 ak[4], aq[4], av[4];
#pragma unroll
      for (int nt=0;nt<4;++nt){ ak[nt]=z4; aq[nt]=z4; av[nt]=z4; }
      const unsigned short* WQ = ws + OFF_QKV + l*49152 + (wave*16+l16)*128;
      const unsigned short* WK = WQ + 16384;
      const unsigned short* WV = WQ + 32768;
#pragma unroll
      for (int ks=0;ks<4;++ks){
        const int k0 = ks*32 + qd*8;
        short8 wq = ld8(WQ + k0);
        short8 wk = ld8(WK + k0);
        short8 wv = ld8(WV + k0);
#pragma unroll
        for (int nt=0;nt<4;++nt){
          short8 bf = ld8(s_a + (nt*16+l16)*PA + k0);
          ak[nt] = mfma(wk, bf, ak[nt]);
          aq[nt] = mfma(wq, bf, aq[nt]);
          av[nt] = mfma(wv, bf, av[nt]);
        }
      }
      const f4 vbk = *(const f4*)(bk + l*128 + ch0);
      const f4 vbq = *(const f4*)(bq + l*128 + ch0);
      const f4 vbv = *(const f4*)(bv + l*128 + ch0);
      unsigned short* Vr = s_tr + 8704;
      const int vbase0 = ch0*72;
#pragma unroll
      for (int nt=0;nt<4;++nt){
        int node = nt*16 + l16;   // garbage rows finite, masked in softmax
        st4(&s_tr[node*136 + ch0], ak[nt] + vbk);
        st4(&s_q[node*PA + ch0], aq[nt] + vbq);
        if (vmask & (1u<<nt)){
          int base = vbase0 + vcolo[nt];
#pragma unroll
          for (int reg=0;reg<4;++reg)
            Vr[base + reg*72] = f2b1(av[nt][reg] + vbv[reg]);
        }
      }
      __syncthreads();   // K/V/Q visible; s_a free for O
    }
    // ---- attention: 24 (pair, mt) units over 8 waves x 3 — balanced.
    //      Swapped QK^T -> register softmax -> swapped PV (packed O st4).
    {
#pragma unroll
      for (int i=0;i<3;++i){
        int u = wave + 8*i;            // 0..23
        int pair = u >> 1, mt = u & 1;
        int b = pair>>2, h = pair&3;
        f4 sc[2]; sc[0]=z4; sc[1]=z4;
        short8 qb = ld8(s_q + (b*21 + mt*16 + l16)*PA + h*32 + qd*8);
#pragma unroll
        for (int nt=0;nt<2;++nt){
          short8 ka = ld8(s_tr + (b*21 + nt*16 + l16)*136 + h*32 + qd*8);
          sc[nt] = mfma(ka, qb, sc[nt]);   // S^T tile: rows k, cols q
        }
        const float scale = 0.1767766952966369f; // 1/sqrt(32)
        float s0[4], s1[4];
        float m = -1e30f;
#pragma unroll
        for (int reg=0;reg<4;++reg){
          s0[reg] = sc[0][reg]*scale;                       // k = qd*4+reg (<16, valid)
          bool kv = (16 + qd*4 + reg) < 21;                 // k = 16+qd*4+reg
          s1[reg] = kv ? sc[1][reg]*scale : -1e30f;
          m = fmaxf(m, fmaxf(s0[reg], s1[reg]));
        }
        m = fmaxf(m, __shfl_xor(m,16));
        m = fmaxf(m, __shfl_xor(m,32));   // max over all k for this q=l16
        float e0[4], e1[4];
        float sum = 0.f;
#pragma unroll
        for (int reg=0;reg<4;++reg){
          e0[reg] = __expf(s0[reg]-m);
          e1[reg] = ((16+qd*4+reg)<21) ? __expf(s1[reg]-m) : 0.f;
          sum += e0[reg]+e1[reg];
        }
        sum += __shfl_xor(sum,16);
        sum += __shfl_xor(sum,32);        // sum over all k for this q=l16
        float rinv = 1.f/sum;             // sum>=1 even for garbage-q lanes (finite)
        if (b < nb){
          uint2v t0, t1;
          t0[0] = pk2(e0[0]*rinv, e0[1]*rinv);
          t0[1] = pk2(e0[2]*rinv, e0[3]*rinv);
          t1[0] = pk2(e1[0]*rinv, e1[1]*rinv);
          t1[1] = pk2(e1[2]*rinv, e1[3]*rinv);
          short4v pa0 = *(short4v*)&t0;
          short4v pa1 = *(short4v*)&t1;
          // PV swapped: A=V^T (row=d), B=P (col=q) -> quad along d.
          f4 oa[2]; oa[0]=z4; oa[1]=z4;
#pragma unroll
          for (int nt=0;nt<2;++nt){
            int ch = h*32 + nt*16 + l16;
            const unsigned short* vp = s_tr + 8704 + ch*72 + b*24;
            short4v vb0 = *(const short4v*)(vp + qd*4);
            short4v vb1 = *(const short4v*)(vp + 16 + qd*4);
            oa[nt] = mfma16(vb0, pa0, oa[nt]);
            oa[nt] = mfma16(vb1, pa1, oa[nt]);
          }
          int q = mt*16 + l16;
          if (q < 21){
            int row = (b*21 + q)*PA + h*32;
#pragma unroll
            for (int nt=0;nt<2;++nt)
              st4(&s_a[row + nt*16 + qd*4], oa[nt]);
          }
        }
      }
      __syncthreads();   // all O stripes visible before Wo
    }
    // ---- Wo: res += O@Wo + bo. Swapped (quad=ch -> packed rmw4).
    {
      f4 ao[1][4];
#pragma unroll
      for (int nt=0;nt<4;++nt) ao[0][nt]=z4;
      chan_mm<1,4,4>(ws + OFF_WO + l*16384, 128, s_a, PA, 0, wave, lane, ao);
      const f4 vbo = *(const f4*)(bo + l*128 + ch0);
#pragma unroll
      for (int nt=0;nt<4;++nt){
        int node = nt*16 + l16;
        if (node < rvalid)
          rmw4(&s_res[node*136 + ch0], ao[0][nt] + vbo);
      }
      __syncthreads();
    }
    // ---- LN2 -> s_a
    layer_norm(s_res, s_a, ln2a + l*128, ln2b + l*128, tid);
    __syncthreads();
    // ---- GraphNet: 2 barriers. WG1 h0+h1 fused (shared A = s_a rows);
    //      WG2 y0/y1 streams interleaved.
    {
      f4 u1[4], u2[4];
#pragma unroll
      for (int mt=0;mt<4;++mt){ u1[mt]=z4; u2[mt]=z4; }
      {
        const unsigned short* W1 = ws + OFF_WG1 + l*32768;
#pragma unroll
        for (int ks=0;ks<4;++ks){
          const int k0 = ks*32 + qd*8;
          short8 af[4];
#pragma unroll
          for (int m=0;m<4;++m) af[m] = ld8(s_a + (m*16+l16)*PA + k0);
          short8 b1 = ld8(W1 + (wave*16+l16)*128 + k0);
          short8 b2 = ld8(W1 + 16384 + (wave*16+l16)*128 + k0);
#pragma unroll
          for (int m=0;m<4;++m){
            u1[m] = mfma(af[m], b1, u1[m]);
            u2[m] = mfma(af[m], b2, u2[m]);
          }
        }
      }
      // half0: stage u1 (own ch rows) -> node -> y0 -> TRU
      {
#pragma unroll
        for (int mt=0;mt<4;++mt) write_tr2(s_tr, chBase, u1[mt], wpack[mt], wmask, mt);
        f4 y[3][2];
#pragma unroll
        for (int b=0;b<3;++b){ y[b][0]=z4; y[b][1]=z4; }
        node_mm1(s_tr, wave, ws + OFF_LG + l*1024, lane, y);
        const f4 vb1 = *(const f4*)(bg1 + l*256 + ch0);
#pragma unroll
        for (int b=0;b<3;++b){ if (b>=nb) continue;
#pragma unroll
          for (int nt=0;nt<2;++nt){
            int o = nt*16+l16;
            if (o<21){ int r = b*21+o;
              st4(&s_tr[TRU + r*PA + ch0], maxz(y[b][nt] + vb1));
            }
          }
        }
      }
      // half1: re-stage own s_tr rows with u2 (wave-local overwrite)
      {
#pragma unroll
        for (int mt=0;mt<4;++mt) write_tr2(s_tr, chBase, u2[mt], wpack[mt], wmask, mt);
        f4 y[3][2];
#pragma unroll
        for (int b=0;b<3;++b){ y[b][0]=z4; y[b][1]=z4; }
        node_mm1(s_tr, wave, ws + OFF_LG + l*1024, lane, y);
        const f4 vb1b = *(const f4*)(bg1 + l*256 + 128 + ch0);
#pragma unroll
        for (int b=0;b<3;++b){ if (b>=nb) continue;
#pragma unroll
          for (int nt=0;nt<2;++nt){
            int o = nt*16+l16;
            if (o<21){ int r = b*21+o;
              st4(&s_y1[r*PA + ch0], maxz(y[b][nt] + vb1b));
            }
          }
        }
      }
      __syncthreads();   // B2: y0(TRU) + y1(s_y1) visible
      // WG2: y0/y1 streams interleaved
      f4 Z[4];
#pragma unroll
      for (int mt=0;mt<4;++mt) Z[mt]=z4;
      {
        const unsigned short* W2 = ws + OFF_WG2 + l*32768;
#pragma unroll
        for (int ks=0;ks<4;++ks){
          const int k0 = ks*32 + qd*8;
          short8 a0[4], a1[4];
#pragma unroll
          for (int m=0;m<4;++m) a0[m] = ld8(s_tr + TRU + (m*16+l16)*PA + k0);
#pragma unroll
          for (int m=0;m<4;++m) a1[m] = ld8(s_y1 + (m*16+l16)*PA + k0);
          short8 b0 = ld8(W2 + (wave*16+l16)*256 + k0);
          short8 b1 = ld8(W2 + (wave*16+l16)*256 + 128 + k0);
#pragma unroll
          for (int m=0;m<4;++m){
            Z[m] = mfma(a0[m], b0, Z[m]);
            Z[m] = mfma(a1[m], b1, Z[m]);
          }
        }
      }
      // Z^T staging into s_tr (own ch rows, wave-local) -> NO barrier
      {
#pragma unroll
        for (int mt=0;mt<4;++mt) write_tr2(s_tr, chBase, Z[mt], wpack[mt], wmask, mt);
      }
      f4 fz[3][2];
#pragma unroll
      for (int b=0;b<3;++b){ fz[b][0]=z4; fz[b][1]=z4; }
      node_mm1(s_tr, wave, ws + OFF_LG + l*1024, lane, fz);   // wave-local
      {
        const f4 vb2 = *(const f4*)(bg2 + l*128 + ch0);
#pragma unroll
        for (int b=0;b<3;++b){ if (b>=nb) continue;
#pragma unroll
          for (int nt=0;nt<2;++nt){
            int o = nt*16+l16;
            if (o<21){ int r = b*21+o;
              rmw4(&s_res[r*136 + ch0], fz[b][nt] + vb2);
            }
          }
        }
      }
      __syncthreads();   // B4: s_res complete
    }
    // ---- ResChebGC: g = relu(cheb1(res)) -> s_a; res += relu(cheb2(g))
    cheb_res(s_res, 136, ws + OFF_WC1 + l*49152, bc1 + l*128, true,
             s_a, s_tr, s_res, M1r, M2r, lane, wave, nb, rvalid,
             chBase, wpack, wmask);
    cheb_res(s_a, PA, ws + OFF_WC2 + l*49152, bc2 + l*128, false,
             s_a, s_tr, s_res, M1r, M2r, lane, wave, nb, rvalid,
             chBase, wpack, wmask);
  }

  // ---- final cheb -> out (fp32), node part in fp32 VALU
  {
    f4 acc = z4;
    if (wave < 4){
#pragma unroll
      for (int ks=0;ks<4;++ks){
        int k0 = ks*32 + qd*8;
        short8 af = ld8(s_res + (wave*16 + l16)*136 + k0);
        short8 bf = ld8(ws + OFF_WOUT + l16*128 + k0);
        acc = mfma(af, bf, acc);
      }
    }
    float* sf = (float*)s_a;
    if (wave < 4 && l16 < 9){
#pragma unroll
      for (int reg=0;reg<4;++reg){
        int r = wave*16 + qd*4 + reg;
        if (r < 63) sf[r*12 + l16] = acc[reg];
      }
    }
    __syncthreads();
    if (tid < 189){
      int r = tid/3, c = tid - r*3;
      int b = (r>=42)?2:((r>=21)?1:0);
      int n = r - b*21;
      if (b < nb){
        const float* M1f = g_ws.m1f;
        const float* M2f = g_ws.m2f;
        float a = sf[r*12 + c] + b_out[c];
        for (int m=0;m<21;++m){
          a += M1f[n*21+m]*sf[(b*21+m)*12 + 3 + c];
          a += M2f[n*21+m]*sf[(b*21+m)*12 + 6 + c];
        }
        out[((long)(blk*3+b)*21 + n)*3 + c] = a;
      }
    }
  }
}

extern "C" void kernel_launch(void* const* d_in, const int* in_sizes, int n_in,
                              void* d_out, int out_size, void* d_ws, size_t ws_size,
                              hipStream_t stream){
  const float* x    = (const float*)d_in[0];
  // d_in[1] = mask (all ones) -- unused
  const float* adj  = (const float*)d_in[2];
  const float* Win  = (const float*)d_in[3];
  const float* b_in = (const float*)d_in[4];
  const float* Wout = (const float*)d_in[5];
  const float* b_out= (const float*)d_in[6];
  const float* ln1a = (const float*)d_in[7];
  const float* ln1b = (const float*)d_in[8];
  const float* ln2a = (const float*)d_in[9];
  const float* ln2b = (const float*)d_in[10];
  const float* Wq = (const float*)d_in[11];
  const float* bq = (const float*)d_in[12];
  const float* Wk = (const float*)d_in[13];
  const float* bk = (const float*)d_in[14];
  const float* Wv = (const float*)d_in[15];
  const float* bv = (const float*)d_in[16];
  const float* Wo = (const float*)d_in[17];
  const float* bo = (const float*)d_in[18];
  const float* Ahat = (const float*)d_in[19];
  const float* Wg1 = (const float*)d_in[20];
  const float* bg1 = (const float*)d_in[21];
  const float* Wg2 = (const float*)d_in[22];
  const float* bg2 = (const float*)d_in[23];
  const float* Wc1 = (const float*)d_in[24];
  const float* bc1 = (const float*)d_in[25];
  const float* Wc2 = (const float*)d_in[26];
  const float* bc2 = (const float*)d_in[27];
  float* outp = (float*)d_out;

  hipLaunchKernelGGL(prep_mats, dim3(1), dim3(512), 0, stream, adj, Ahat);
  hipLaunchKernelGGL(prep_tw, dim3(512), dim3(256), 0, stream,
                     Wq, Wk, Wv, Wo, Wg1, Wg2, Wc1, Wc2, Win, Wout);
  hipLaunchKernelGGL(graformer_main, dim3(2731), dim3(512), 0, stream,
                     x, ln1a, ln1b, ln2a, ln2b, bq, bk, bv, bo,
                     bg1, bg2, bc1, bc2, b_in, b_out, outp);
}